// Round 13
// baseline (377.538 us; speedup 1.0000x reference)
//
#include <hip/hip_runtime.h>
#include <math.h>
#include <stddef.h>

#define NFRM 4096   // B*T
#define NBATCH 16

typedef __attribute__((ext_vector_type(8))) short short8v;
typedef __attribute__((ext_vector_type(4))) float f32x4;
#define MFMA_BF16(a,b,c) __builtin_amdgcn_mfma_f32_16x16x32_bf16(a,b,c,0,0,0)

__device__ inline float wsum64(float v){
  #pragma unroll
  for(int m=32;m>=1;m>>=1) v += __shfl_xor(v, m, 64);
  return v;
}

__device__ inline float pe_val(int t,int d){
  int k = d >> 1;
  float div = expf(-(float)(2*k) * (9.210340371976184f/128.f));
  float ang = (float)t * div;
  return (d & 1) ? cosf(ang) : sinf(ang);
}

// split x into hi+lo bf16 (round-to-nearest-even)
__device__ inline void bf16split(float x, unsigned short &h, unsigned short &l){
  unsigned u = __float_as_uint(x);
  unsigned r = (u + 0x7FFFu + ((u>>16)&1u)) & 0xFFFF0000u;
  h = (unsigned short)(r>>16);
  float rem = x - __uint_as_float(r);
  unsigned u2 = __float_as_uint(rem);
  unsigned r2 = (u2 + 0x7FFFu + ((u2>>16)&1u));
  l = (unsigned short)(r2>>16);
}

// ---------------- fused pack: all 4 FFN weights into MFMA B-fragment layout (hi/lo bf16)
__global__ __launch_bounds__(64) void pack_all_kernel(
    const float* __restrict__ spf1w, const float* __restrict__ spf2w,
    const float* __restrict__ tpf1w, const float* __restrict__ tpf2w,
    unsigned short* __restrict__ sp1h, unsigned short* __restrict__ sp1l,
    unsigned short* __restrict__ sp2h, unsigned short* __restrict__ sp2l,
    unsigned short* __restrict__ tp1h, unsigned short* __restrict__ tp1l,
    unsigned short* __restrict__ tp2h, unsigned short* __restrict__ tp2l)
{
  int b = blockIdx.x, lane = threadIdx.x;
  const float* w; unsigned short *hi, *lo; int K, N, ntile, s;
  if(b < 256){        w=spf1w; hi=sp1h; lo=sp1l; K=64;   N=2048; ntile=b&127;        s=b>>7; }
  else if(b < 512){   int bb=b-256;  w=spf2w; hi=sp2h; lo=sp2l; K=2048; N=64;   ntile=bb&3;   s=bb>>2; }
  else if(b < 1024){  int bb=b-512;  w=tpf1w; hi=tp1h; lo=tp1l; K=128;  N=2048; ntile=bb&127; s=bb>>7; }
  else {              int bb=b-1024; w=tpf2w; hi=tp2h; lo=tp2l; K=2048; N=128;  ntile=bb&7;   s=bb>>3; }
  int n = ntile*16 + (lane & 15);
  int k0 = s*32 + (lane>>4)*8;
  size_t off = (((size_t)ntile*(K/32) + s)*64 + lane)*8;
  #pragma unroll
  for(int e=0;e<8;e++){
    float v = w[(size_t)(k0+e)*N + n];
    unsigned short h,l;
    bf16split(v,h,l);
    hi[off+e]=h; lo[off+e]=l;
  }
}

// ---------------- MFMA FFN partial: P[s] = relu(X@W1+b1)[:,slice] @ W2[slice,:]
template<int D, int NS>
__global__ __launch_bounds__(256) void ffn_mfma_partial(
    const float* __restrict__ X, float* __restrict__ P,
    const unsigned short* __restrict__ w1h, const unsigned short* __restrict__ w1l,
    const float* __restrict__ b1,
    const unsigned short* __restrict__ w2h, const unsigned short* __restrict__ w2l)
{
  constexpr int TM=32, JC=128;
  constexpr int KS1 = D/32;
  constexpr int NT2W = (D/16)/4;
  constexpr int HS = 2048/NS;
  constexpr int NCH = HS/JC;
  constexpr int HP = JC + 8;
  __shared__ unsigned short Hh[TM][HP];
  __shared__ unsigned short Hl[TM][HP];
  int tid = threadIdx.x;
  int lane = tid & 63, w = tid >> 6;
  int ar = lane & 15, ak = lane >> 4;
  size_t Ntok = (size_t)gridDim.x*TM;
  const float* Xb = X + (size_t)blockIdx.x*TM*D;

  short8v xah[2][KS1], xal[2][KS1];
  #pragma unroll
  for(int mt=0;mt<2;mt++){
    #pragma unroll
    for(int s=0;s<KS1;s++){
      const float* xp = Xb + (size_t)(mt*16+ar)*D + s*32 + ak*8;
      #pragma unroll
      for(int e=0;e<8;e++){
        unsigned short h,l;
        bf16split(xp[e],h,l);
        xah[mt][s][e]=(short)h; xal[mt][s][e]=(short)l;
      }
    }
  }

  f32x4 acc2[2][NT2W];
  #pragma unroll
  for(int mt=0;mt<2;mt++)
    #pragma unroll
    for(int nt=0;nt<NT2W;nt++)
      acc2[mt][nt] = (f32x4){0.f,0.f,0.f,0.f};

  for(int ch=0; ch<NCH; ch++){
    int jc = blockIdx.y*HS + ch*JC;
    f32x4 a1[2][2];
    #pragma unroll
    for(int mt=0;mt<2;mt++){ a1[mt][0]=(f32x4){0,0,0,0}; a1[mt][1]=(f32x4){0,0,0,0}; }
    #pragma unroll
    for(int s=0;s<KS1;s++){
      #pragma unroll
      for(int nt=0;nt<2;nt++){
        int ntile1 = (jc + w*32 + nt*16) >> 4;
        size_t off = (((size_t)ntile1*KS1 + s)*64 + lane)*8;
        short8v bh = *(const short8v*)(w1h + off);
        short8v bl = *(const short8v*)(w1l + off);
        #pragma unroll
        for(int mt=0;mt<2;mt++){
          a1[mt][nt] = MFMA_BF16(xah[mt][s], bh, a1[mt][nt]);
          a1[mt][nt] = MFMA_BF16(xah[mt][s], bl, a1[mt][nt]);
          a1[mt][nt] = MFMA_BF16(xal[mt][s], bh, a1[mt][nt]);
        }
      }
    }
    __syncthreads();
    #pragma unroll
    for(int nt=0;nt<2;nt++){
      int colBase = w*32 + nt*16 + ar;
      float bval = b1[jc + colBase];
      #pragma unroll
      for(int mt=0;mt<2;mt++){
        #pragma unroll
        for(int r=0;r<4;r++){
          float hv = a1[mt][nt][r] + bval;
          hv = fmaxf(hv, 0.f);
          unsigned short h,l;
          bf16split(hv,h,l);
          int row = mt*16 + ak*4 + r;
          Hh[row][colBase]=h; Hl[row][colBase]=l;
        }
      }
    }
    __syncthreads();
    #pragma unroll
    for(int s2=0;s2<4;s2++){
      short8v ah[2], al[2];
      #pragma unroll
      for(int mt=0;mt<2;mt++){
        ah[mt] = *(const short8v*)&Hh[mt*16+ar][s2*32 + ak*8];
        al[mt] = *(const short8v*)&Hl[mt*16+ar][s2*32 + ak*8];
      }
      #pragma unroll
      for(int nt=0;nt<NT2W;nt++){
        int ntile2 = w*NT2W + nt;
        int kstep2 = (jc >> 5) + s2;
        size_t off = (((size_t)ntile2*64 + kstep2)*64 + lane)*8;
        short8v bh = *(const short8v*)(w2h + off);
        short8v bl = *(const short8v*)(w2l + off);
        #pragma unroll
        for(int mt=0;mt<2;mt++){
          acc2[mt][nt] = MFMA_BF16(ah[mt], bh, acc2[mt][nt]);
          acc2[mt][nt] = MFMA_BF16(ah[mt], bl, acc2[mt][nt]);
          acc2[mt][nt] = MFMA_BF16(al[mt], bh, acc2[mt][nt]);
        }
      }
    }
  }
  float* Pb = P + (size_t)blockIdx.y*Ntok*D + (size_t)blockIdx.x*TM*D;
  #pragma unroll
  for(int mt=0;mt<2;mt++){
    #pragma unroll
    for(int nt=0;nt<NT2W;nt++){
      int col = (w*NT2W + nt)*16 + ar;
      #pragma unroll
      for(int r=0;r<4;r++){
        int row = mt*16 + ak*4 + r;
        Pb[(size_t)row*D + col] = acc2[mt][nt][r];
      }
    }
  }
}

// ---------------- combine partials: Y = LN(X + sum_s P_s + b2)  (temporal path)
template<int D, int NS>
__global__ __launch_bounds__(256) void ffn_combine_kernel(
    const float* __restrict__ X, const float* __restrict__ P,
    float* __restrict__ Y,
    const float* __restrict__ b2,
    const float* __restrict__ lg, const float* __restrict__ lb)
{
  constexpr int EPL = D/64;
  int tid=threadIdx.x;
  int lane = tid & 63;
  size_t Ntok = (size_t)gridDim.x*4;
  size_t row = (size_t)blockIdx.x*4 + (tid>>6);
  size_t base = row*D;
  float e[EPL];
  float s=0.f;
  #pragma unroll
  for(int i=0;i<EPL;i++){
    int c = i*64+lane;
    float v = X[base+c] + b2[c];
    #pragma unroll
    for(int sp=0;sp<NS;sp++) v += P[(size_t)sp*Ntok*D + base + c];
    e[i]=v; s+=v;
  }
  float mm = wsum64(s)*(1.f/D);
  float s2=0.f;
  #pragma unroll
  for(int i=0;i<EPL;i++){ float d=e[i]-mm; s2+=d*d; }
  float rs = rsqrtf(wsum64(s2)*(1.f/D)+1e-5f);
  #pragma unroll
  for(int i=0;i<EPL;i++){
    int c=i*64+lane;
    Y[base+c] = (e[i]-mm)*rs*lg[c]+lb[c];
  }
}

// ---------------- GCN body: wave-synchronous LDS pipeline, compile-time N, F frames per wave
template<int N, int F>
__device__ inline void gcn_run(
    int f0, int rr, const float* __restrict__ xr,
    const float* __restrict__ g1w,const float* __restrict__ g1b,
    const float* __restrict__ g2w,const float* __restrict__ g2b,
    const float* __restrict__ rg,const float* __restrict__ rb,
    float* __restrict__ tok,
    float* xsw, float* t0gw, float* t1w, float (*Cw)[5], int lane)
{
  int c = lane & 31;
  float W1c[11], W2c[32];
  #pragma unroll
  for(int k=0;k<11;k++) W1c[k]=g1w[rr*352 + k*32 + c];
  #pragma unroll
  for(int k=0;k<32;k++) W2c[k]=g2w[rr*1024 + k*32 + c];
  float b1c = g1b[rr*32+c], b2c = g2b[rr*32+c];
  float rgv = rg[rr*64+lane], rbv = rb[rr*64+lane];

  // per-wave adjacency coefs (amortized across F frames)
  #pragma unroll
  for(int ii=0; ii<(N*5+63)/64; ii++){
    int i = lane + ii*64;
    if(i<N*5){
      int node=i/5, j=i%5, m=node+j-2;
      float cf=0.f;
      if(m>=0 && m<N){
        int di = 1 + min(node,2) + min(N-1-node,2);
        int dm = 1 + min(m,2) + min(N-1-m,2);
        cf = rsqrtf((float)(di*dm));
      }
      Cw[node][j]=cf;
    }
  }
  // zero guard rows (amortized)
  #pragma unroll
  for(int ii=0; ii<2; ii++){
    int i = lane + ii*64;
    int row4=i>>5, col=i&31;
    int row = (row4<2) ? row4 : (N+row4);
    t0gw[row*32+col]=0.f;
  }

  for(int it=0; it<F; it++){
    int f = f0 + it;
    // load x padded to stride 12
    #pragma unroll
    for(int ii=0; ii<(N*12+63)/64; ii++){
      int i = lane + ii*64;
      if(i<N*12){
        int node=i/12, k=i-node*12;
        xsw[i] = (k<11) ? xr[(size_t)f*N*11 + node*11 + k] : 0.f;
      }
    }
    __builtin_amdgcn_wave_barrier();
    // GEMM1: t0g interior = x @ W1
    #pragma unroll
    for(int ii=0; ii<(N*32+63)/64; ii++){
      int i = lane + ii*64;
      if(i<N*32){
        int node=i>>5;
        float4 xa = *(const float4*)&xsw[node*12];
        float4 xb = *(const float4*)&xsw[node*12+4];
        float4 xc = *(const float4*)&xsw[node*12+8];
        float s = xa.x*W1c[0]+xa.y*W1c[1]+xa.z*W1c[2]+xa.w*W1c[3]
                + xb.x*W1c[4]+xb.y*W1c[5]+xb.z*W1c[6]+xb.w*W1c[7]
                + xc.x*W1c[8]+xc.y*W1c[9]+xc.z*W1c[10];
        t0gw[(node+2)*32+c]=s;
      }
    }
    __builtin_amdgcn_wave_barrier();
    // A1: t1 = relu(A @ t0 + b1), branch-free 5-tap
    #pragma unroll
    for(int ii=0; ii<(N*32+63)/64; ii++){
      int i = lane + ii*64;
      if(i<N*32){
        int node=i>>5;
        float s=b1c;
        #pragma unroll
        for(int j=0;j<5;j++) s += Cw[node][j]*t0gw[(node+j)*32+c];
        t1w[i]=fmaxf(s,0.f);
      }
    }
    __builtin_amdgcn_wave_barrier();
    // GEMM2: t0g interior = t1 @ W2
    #pragma unroll
    for(int ii=0; ii<(N*32+63)/64; ii++){
      int i = lane + ii*64;
      if(i<N*32){
        int node=i>>5;
        float s=0.f;
        #pragma unroll
        for(int k0=0;k0<32;k0+=4){
          float4 tv = *(const float4*)&t1w[node*32+k0];
          s += tv.x*W2c[k0] + tv.y*W2c[k0+1] + tv.z*W2c[k0+2] + tv.w*W2c[k0+3];
        }
        t0gw[(node+2)*32+c]=s;
      }
    }
    __builtin_amdgcn_wave_barrier();
    // A2: t1 = relu(A @ t0 + b2)
    #pragma unroll
    for(int ii=0; ii<(N*32+63)/64; ii++){
      int i = lane + ii*64;
      if(i<N*32){
        int node=i>>5;
        float s=b2c;
        #pragma unroll
        for(int j=0;j<5;j++) s += Cw[node][j]*t0gw[(node+j)*32+c];
        t1w[i]=fmaxf(s,0.f);
      }
    }
    __builtin_amdgcn_wave_barrier();
    // pool + LN + write
    float v;
    if(lane<32){
      float s=0.f;
      #pragma unroll
      for(int m=0;m<N;m++) s += t1w[m*32+lane];
      v = s*(1.f/(float)N);
    } else {
      float mx=-1e30f;
      #pragma unroll
      for(int m=0;m<N;m++) mx = fmaxf(mx, t1w[m*32+c]);
      v = mx;
    }
    float m1 = wsum64(v)*(1.f/64.f);
    float d1 = v - m1;
    float var = wsum64(d1*d1)*(1.f/64.f);
    float y = d1*rsqrtf(var+1e-5f)*rgv + rbv;
    tok[((size_t)f*6+rr)*64+lane] = y;
    __builtin_amdgcn_wave_barrier();
  }
}

// ---------------- Kernel 1: GCN — 2 waves/block, F=4 frames per wave
__global__ __launch_bounds__(128) void gcn_kernel(
    const float* __restrict__ x0,const float* __restrict__ x1,
    const float* __restrict__ x2,const float* __restrict__ x3,
    const float* __restrict__ x4,const float* __restrict__ x5,
    const float* __restrict__ g1w,const float* __restrict__ g1b,
    const float* __restrict__ g2w,const float* __restrict__ g2b,
    const float* __restrict__ rg,const float* __restrict__ rb,
    float* __restrict__ tok)
{
  constexpr int F = 4;
  int tid=threadIdx.x;
  int lane = tid & 63, w = tid >> 6;
  int f0 = (blockIdx.x*2 + w)*F;
  int r = blockIdx.y;
  __shared__ float xs[2][240];
  __shared__ float t0g[2][768];
  __shared__ float t1s[2][640];
  __shared__ float Cs[2][20][5];
  float* xsw = &xs[w][0];
  float* t0gw = &t0g[w][0];
  float* t1w = &t1s[w][0];
  float (*Cw)[5] = Cs[w];
  if(r==5)      gcn_run<20,F>(f0,r,x5,g1w,g1b,g2w,g2b,rg,rb,tok,xsw,t0gw,t1w,Cw,lane);
  else if(r==2) gcn_run<11,F>(f0,r,x2,g1w,g1b,g2w,g2b,rg,rb,tok,xsw,t0gw,t1w,Cw,lane);
  else if(r==3) gcn_run<11,F>(f0,r,x3,g1w,g1b,g2w,g2b,rg,rb,tok,xsw,t0gw,t1w,Cw,lane);
  else if(r==0) gcn_run<9,F>(f0,r,x0,g1w,g1b,g2w,g2b,rg,rb,tok,xsw,t0gw,t1w,Cw,lane);
  else if(r==1) gcn_run<9,F>(f0,r,x1,g1w,g1b,g2w,g2b,rg,rb,tok,xsw,t0gw,t1w,Cw,lane);
  else          gcn_run<9,F>(f0,r,x4,g1w,g1b,g2w,g2b,rg,rb,tok,xsw,t0gw,t1w,Cw,lane);
}

// ---------------- Kernel 2a: spatial attention + residual + LN1 — 4 frames/block, block-wide GEMMs
__global__ __launch_bounds__(256) void sp_attn_kernel(
    float* __restrict__ tok,
    const float* __restrict__ qkvw,const float* __restrict__ qkvb,
    const float* __restrict__ ow,const float* __restrict__ ob,
    const float* __restrict__ l1g,const float* __restrict__ l1b)
{
  __shared__ float Xs[24][64];
  __shared__ float QKV[24][192];
  __shared__ float SC[4][144];
  __shared__ float AO[24][64];
  int tid=threadIdx.x;
  int f0 = blockIdx.x*4;
  float* Xf = &Xs[0][0];
  for(int i=tid;i<1536;i+=256) Xf[i] = tok[(size_t)f0*384 + i];
  __syncthreads();
  {
    int cg = tid & 31, c0 = cg*6;
    int rg = tid >> 5, r0 = rg*3;
    float acc[3][6];
    #pragma unroll
    for(int m=0;m<3;m++)
      #pragma unroll
      for(int j=0;j<6;j++) acc[m][j]=qkvb[c0+j];
    for(int k=0;k<64;k++){
      float wv[6];
      #pragma unroll
      for(int j=0;j<6;j++) wv[j]=qkvw[k*192+c0+j];
      float xv0=Xs[r0][k], xv1=Xs[r0+1][k], xv2=Xs[r0+2][k];
      #pragma unroll
      for(int j=0;j<6;j++){
        acc[0][j]+=xv0*wv[j];
        acc[1][j]+=xv1*wv[j];
        acc[2][j]+=xv2*wv[j];
      }
    }
    #pragma unroll
    for(int m=0;m<3;m++)
      #pragma unroll
      for(int j=0;j<6;j++) QKV[r0+m][c0+j]=acc[m][j];
  }
  __syncthreads();
  for(int i=tid;i<576;i+=256){
    int fr=i/144, rest=i%144;
    int h=rest/36, qi=(rest%36)/6, ki=rest%6;
    float s=0.f;
    #pragma unroll
    for(int d=0;d<16;d++) s += QKV[fr*6+qi][h*16+d]*QKV[fr*6+ki][64+h*16+d];
    SC[fr][rest]=s*0.25f;
  }
  __syncthreads();
  if(tid<96){
    int fr=tid/24, idx=tid%24;
    int base=idx*6;
    float mx=-1e30f;
    for(int k=0;k<6;k++) mx=fmaxf(mx,SC[fr][base+k]);
    float sm=0.f;
    for(int k=0;k<6;k++){ float e=expf(SC[fr][base+k]-mx); SC[fr][base+k]=e; sm+=e; }
    float rr=1.f/sm;
    for(int k=0;k<6;k++) SC[fr][base+k]*=rr;
  }
  __syncthreads();
  for(int i=tid;i<1536;i+=256){
    int fr=i/384, rem=i%384;
    int row=rem/64, c=rem&63, h=c/16;
    float s=0.f;
    #pragma unroll
    for(int k=0;k<6;k++) s += SC[fr][h*36+row*6+k]*QKV[fr*6+k][128+c];
    AO[fr*6+row][c]=s;
  }
  __syncthreads();
  {
    int cg = tid & 31, c0 = cg*2;
    int rg = tid >> 5, r0 = rg*3;
    float acc[3][2];
    #pragma unroll
    for(int m=0;m<3;m++){ acc[m][0]=ob[c0]; acc[m][1]=ob[c0+1]; }
    for(int k=0;k<64;k++){
      float w0=ow[k*64+c0], w1=ow[k*64+c0+1];
      float a0=AO[r0][k], a1=AO[r0+1][k], a2=AO[r0+2][k];
      acc[0][0]+=a0*w0; acc[0][1]+=a0*w1;
      acc[1][0]+=a1*w0; acc[1][1]+=a1*w1;
      acc[2][0]+=a2*w0; acc[2][1]+=a2*w1;
    }
    #pragma unroll
    for(int m=0;m<3;m++){
      QKV[r0+m][c0]   = Xs[r0+m][c0]   + acc[m][0];
      QKV[r0+m][c0+1] = Xs[r0+m][c0+1] + acc[m][1];
    }
  }
  __syncthreads();
  {
    int lane = tid & 63, w = tid >> 6;
    #pragma unroll
    for(int rr=0;rr<6;rr++){
      int row = w*6+rr;
      float v=QKV[row][lane];
      float mm=wsum64(v)*(1.f/64.f);
      float d=v-mm;
      float var=wsum64(d*d)*(1.f/64.f);
      tok[(size_t)f0*384 + row*64 + lane]=d*rsqrtf(var+1e-5f)*l1g[lane]+l1b[lane];
    }
  }
}

// ---------------- fused fp32 FFN + residual + LN (fallback path)
template<int D, int TM>
__global__ __launch_bounds__(256) void ffn_ln_kernel(
    const float* __restrict__ X, float* __restrict__ Yout,
    const float* __restrict__ w1,const float* __restrict__ b1,
    const float* __restrict__ w2,const float* __restrict__ b2,
    const float* __restrict__ lg,const float* __restrict__ lb)
{
  constexpr int JC = 128;
  constexpr int JS = JC + 4;
  constexpr int M1 = TM/8;
  constexpr int CG = D/4;
  constexpr int MG2 = 256/CG;
  constexpr int M2 = TM/MG2;
  __shared__ float Xs[TM*D];
  __shared__ float Hs[TM*JS];
  int tid=threadIdx.x;
  const float* Xb = X + (size_t)blockIdx.x*TM*D;
  for(int i=tid;i<TM*D;i+=256) Xs[i]=Xb[i];

  int jg = tid & 31, j0 = jg*4;
  int mg1 = tid >> 5;
  int m10 = mg1*M1;
  int cg = tid % CG, c0 = cg*4;
  int mg2 = tid / CG;
  int m20 = mg2*M2;

  float acc[M2][4];
  #pragma unroll
  for(int m=0;m<M2;m++){ acc[m][0]=0.f;acc[m][1]=0.f;acc[m][2]=0.f;acc[m][3]=0.f; }

  __syncthreads();
  for(int jc=0;jc<2048;jc+=JC){
    float a1[M1][4];
    float4 bv = *(const float4*)&b1[jc+j0];
    #pragma unroll
    for(int m=0;m<M1;m++){ a1[m][0]=bv.x;a1[m][1]=bv.y;a1[m][2]=bv.z;a1[m][3]=bv.w; }
    for(int k0=0;k0<D;k0+=4){
      float4 wr0 = *(const float4*)&w1[(size_t)(k0+0)*2048 + jc + j0];
      float4 wr1 = *(const float4*)&w1[(size_t)(k0+1)*2048 + jc + j0];
      float4 wr2 = *(const float4*)&w1[(size_t)(k0+2)*2048 + jc + j0];
      float4 wr3 = *(const float4*)&w1[(size_t)(k0+3)*2048 + jc + j0];
      #pragma unroll
      for(int m=0;m<M1;m++){
        float4 xv = *(const float4*)&Xs[(m10+m)*D + k0];
        a1[m][0] += xv.x*wr0.x + xv.y*wr1.x + xv.z*wr2.x + xv.w*wr3.x;
        a1[m][1] += xv.x*wr0.y + xv.y*wr1.y + xv.z*wr2.y + xv.w*wr3.y;
        a1[m][2] += xv.x*wr0.z + xv.y*wr1.z + xv.z*wr2.z + xv.w*wr3.z;
        a1[m][3] += xv.x*wr0.w + xv.y*wr1.w + xv.z*wr2.w + xv.w*wr3.w;
      }
    }
    #pragma unroll
    for(int m=0;m<M1;m++){
      float4 hv;
      hv.x=fmaxf(a1[m][0],0.f); hv.y=fmaxf(a1[m][1],0.f);
      hv.z=fmaxf(a1[m][2],0.f); hv.w=fmaxf(a1[m][3],0.f);
      *(float4*)&Hs[(m10+m)*JS + j0] = hv;
    }
    __syncthreads();
    for(int jj0=0;jj0<JC;jj0+=4){
      float4 w20 = *(const float4*)&w2[(size_t)(jc+jj0+0)*D + c0];
      float4 w21 = *(const float4*)&w2[(size_t)(jc+jj0+1)*D + c0];
      float4 w22 = *(const float4*)&w2[(size_t)(jc+jj0+2)*D + c0];
      float4 w23 = *(const float4*)&w2[(size_t)(jc+jj0+3)*D + c0];
      #pragma unroll
      for(int m=0;m<M2;m++){
        float4 hv = *(const float4*)&Hs[(m20+m)*JS + jj0];
        acc[m][0] += hv.x*w20.x + hv.y*w21.x + hv.z*w22.x + hv.w*w23.x;
        acc[m][1] += hv.x*w20.y + hv.y*w21.y + hv.z*w22.y + hv.w*w23.y;
        acc[m][2] += hv.x*w20.z + hv.y*w21.z + hv.z*w22.z + hv.w*w23.z;
        acc[m][3] += hv.x*w20.w + hv.y*w21.w + hv.z*w22.w + hv.w*w23.w;
      }
    }
    __syncthreads();
  }
  {
    float4 b2v = *(const float4*)&b2[c0];
    #pragma unroll
    for(int m=0;m<M2;m++){
      int row = m20+m;
      float4 xv = *(const float4*)&Xs[row*D + c0];
      float4 yv;
      yv.x = xv.x + acc[m][0] + b2v.x;
      yv.y = xv.y + acc[m][1] + b2v.y;
      yv.z = xv.z + acc[m][2] + b2v.z;
      yv.w = xv.w + acc[m][3] + b2v.w;
      *(float4*)&Hs[row*D + c0] = yv;
    }
  }
  __syncthreads();
  constexpr int EPL = D/64;
  int lane = tid & 63, wv = tid >> 6;
  float* Yb = Yout + (size_t)blockIdx.x*TM*D;
  for(int row=wv; row<TM; row+=4){
    float e[EPL];
    float s=0.f;
    #pragma unroll
    for(int i=0;i<EPL;i++){ e[i]=Hs[row*D + i*64 + lane]; s+=e[i]; }
    float mm = wsum64(s)*(1.f/D);
    float s2=0.f;
    #pragma unroll
    for(int i=0;i<EPL;i++){ float d=e[i]-mm; s2+=d*d; }
    float rs = rsqrtf(wsum64(s2)*(1.f/D)+1e-5f);
    #pragma unroll
    for(int i=0;i<EPL;i++)
      Yb[row*D + i*64 + lane] = (e[i]-mm)*rs*lg[i*64+lane]+lb[i*64+lane];
  }
}

// ---------------- Kernel 3: fuse — 4 frames/block; inlines spatial FFN combine (partials+b2+LN2)
__global__ __launch_bounds__(256) void fuse_kernel(
    const float* __restrict__ tok, const float* __restrict__ part, int do_combine,
    const float* __restrict__ sb2, const float* __restrict__ sl2g, const float* __restrict__ sl2b,
    const float* __restrict__ gfeat,
    const float* __restrict__ alpha_p, const float* __restrict__ rlogit,
    const float* __restrict__ g1w,const float* __restrict__ g1b,
    const float* __restrict__ g2w,const float* __restrict__ g2b,
    const float* __restrict__ caqw,const float* __restrict__ caqb,
    const float* __restrict__ caow,const float* __restrict__ caob,
    const float* __restrict__ calng,const float* __restrict__ calnb,
    const float* __restrict__ gw,const float* __restrict__ gb,
    const float* __restrict__ glng,const float* __restrict__ glnb,
    const float* __restrict__ flng,const float* __restrict__ flnb,
    float* __restrict__ fused)
{
  int tid=threadIdx.x;
  int lane = tid & 63, w = tid >> 6;
  int f = blockIdx.x*4 + w;
  __shared__ float X[4][384];
  __shared__ float G1[4][192];
  __shared__ float gt[4][6];
  __shared__ float qv[4][64];
  __shared__ float Qs[4][64];
  __shared__ float KK[4][384], VV[4][384];
  __shared__ float sc[4][24];
  __shared__ float AOs[4][64];

  const float* trow = tok + (size_t)f*384;
  if(do_combine){
    #pragma unroll
    for(int row=0;row<6;row++){
      size_t grow = (size_t)f*6 + row;
      float v = trow[row*64+lane] + sb2[lane]
              + part[grow*64 + lane]
              + part[(size_t)24576*64 + grow*64 + lane];
      float mm = wsum64(v)*(1.f/64.f);
      float d = v-mm;
      float var = wsum64(d*d)*(1.f/64.f);
      X[w][row*64+lane] = d*rsqrtf(var+1e-5f)*sl2g[lane]+sl2b[lane];
    }
  } else {
    for(int i=lane;i<384;i+=64) X[w][i]=trow[i];
  }
  __syncthreads();
  for(int i=lane;i<192;i+=64){
    int rr=i/32, j=i%32;
    float s=g1b[j];
    #pragma unroll
    for(int k=0;k<64;k++) s += X[w][rr*64+k]*g1w[k*32+j];
    G1[w][i]=fmaxf(s,0.f);
  }
  __syncthreads();
  if(lane<6){
    float s=g2b[0];
    #pragma unroll
    for(int k=0;k<32;k++) s += G1[w][lane*32+k]*g2w[k];
    float gate = 1.f/(1.f+expf(-s));
    float rw = log1pf(expf(rlogit[lane]));
    gt[w][lane]=gate*rw;
  }
  __syncthreads();
  for(int i=lane;i<384;i+=64) X[w][i]*=gt[w][i/64];
  __syncthreads();
  {
    float s=0.f;
    #pragma unroll
    for(int rr=0;rr<6;rr++) s+=X[w][rr*64+lane];
    qv[w][lane]=s*(1.f/6.f);
  }
  __syncthreads();
  {
    float s=caqb[lane];
    #pragma unroll
    for(int k=0;k<64;k++) s += qv[w][k]*caqw[k*192+lane];
    Qs[w][lane]=s;
  }
  for(int i=lane;i<384;i+=64){
    int rr=i/64, c=i%64;
    float sk=caqb[64+c], sv=caqb[128+c];
    #pragma unroll
    for(int k=0;k<64;k++){
      float xv=X[w][rr*64+k];
      sk += xv*caqw[k*192+64+c];
      sv += xv*caqw[k*192+128+c];
    }
    KK[w][i]=sk; VV[w][i]=sv;
  }
  __syncthreads();
  if(lane<24){
    int h=lane/6, ki=lane%6;
    float s=0.f;
    #pragma unroll
    for(int d=0;d<16;d++) s += Qs[w][h*16+d]*KK[w][ki*64+h*16+d];
    sc[w][lane]=s*0.25f;
  }
  __syncthreads();
  if(lane<4){
    float mx=-1e30f;
    for(int k=0;k<6;k++) mx=fmaxf(mx,sc[w][lane*6+k]);
    float sm=0.f;
    for(int k=0;k<6;k++){ float e=expf(sc[w][lane*6+k]-mx); sc[w][lane*6+k]=e; sm+=e; }
    float rr=1.f/sm;
    for(int k=0;k<6;k++) sc[w][lane*6+k]*=rr;
  }
  __syncthreads();
  {
    int h=lane/16;
    float s=0.f;
    #pragma unroll
    for(int k=0;k<6;k++) s += sc[w][h*6+k]*VV[w][k*64+lane];
    AOs[w][lane]=s;
  }
  __syncthreads();
  float pr;
  {
    float s=caob[lane];
    #pragma unroll
    for(int k=0;k<64;k++) s += AOs[w][k]*caow[k*64+lane];
    pr = qv[w][lane] + s;
  }
  float m1=wsum64(pr)*(1.f/64.f);
  float d1=pr-m1;
  float v1=wsum64(d1*d1)*(1.f/64.f);
  float fr = d1*rsqrtf(v1+1e-5f)*calng[lane]+calnb[lane];
  float gvv;
  {
    float s=gb[lane];
    #pragma unroll
    for(int k=0;k<4;k++) s += gfeat[(size_t)f*4+k]*gw[k*64+lane];
    gvv=s;
  }
  float m2=wsum64(gvv)*(1.f/64.f);
  float d2=gvv-m2;
  float v2=wsum64(d2*d2)*(1.f/64.f);
  float gg = fmaxf(d2*rsqrtf(v2+1e-5f)*glng[lane]+glnb[lane],0.f)*tanhf(alpha_p[0]);
  float sm_ = wsum64(fr+gg)*(1.f/128.f);
  float da=fr-sm_, db=gg-sm_;
  float vv = wsum64(da*da+db*db)*(1.f/128.f);
  float rs = rsqrtf(vv+1e-5f);
  int t = f & 255;
  fused[(size_t)f*128+lane]     = da*rs*flng[lane]+flnb[lane]         + pe_val(t,lane);
  fused[(size_t)f*128+64+lane]  = db*rs*flng[64+lane]+flnb[64+lane]   + pe_val(t,64+lane);
}

// ---------------- temporal QKV: Y = X@W + b  (grid (128, 3): oc chunk per blockIdx.y)
__global__ __launch_bounds__(256) void tqkv_gemm_kernel(
    const float* __restrict__ X, float* __restrict__ Y,
    const float* __restrict__ w, const float* __restrict__ b)
{
  __shared__ float Xs[32*128];
  int tid=threadIdx.x;
  const float* Xb = X + (size_t)blockIdx.x*32*128;
  for(int i=tid;i<4096;i+=256) Xs[i]=Xb[i];
  __syncthreads();
  int cg = tid & 31, c0 = cg*4;
  int mg = tid >> 5, m0 = mg*4;
  float* Yb = Y + (size_t)blockIdx.x*32*384;
  int oc = blockIdx.y*128;
  float acc[4][4];
  float4 bv = *(const float4*)&b[oc+c0];
  #pragma unroll
  for(int m=0;m<4;m++){ acc[m][0]=bv.x;acc[m][1]=bv.y;acc[m][2]=bv.z;acc[m][3]=bv.w; }
  for(int k0=0;k0<128;k0+=4){
    float4 w0 = *(const float4*)&w[(k0+0)*384 + oc + c0];
    float4 w1 = *(const float4*)&w[(k0+1)*384 + oc + c0];
    float4 w2 = *(const float4*)&w[(k0+2)*384 + oc + c0];
    float4 w3 = *(const float4*)&w[(k0+3)*384 + oc + c0];
    #pragma unroll
    for(int m=0;m<4;m++){
      float4 xv = *(const float4*)&Xs[(m0+m)*128 + k0];
      acc[m][0] += xv.x*w0.x + xv.y*w1.x + xv.z*w2.x + xv.w*w3.x;
      acc[m][1] += xv.x*w0.y + xv.y*w1.y + xv.z*w2.y + xv.w*w3.y;
      acc[m][2] += xv.x*w0.z + xv.y*w1.z + xv.z*w2.z + xv.w*w3.z;
      acc[m][3] += xv.x*w0.w + xv.y*w1.w + xv.z*w2.w + xv.w*w3.w;
    }
  }
  #pragma unroll
  for(int m=0;m<4;m++){
    float4 yv; yv.x=acc[m][0];yv.y=acc[m][1];yv.z=acc[m][2];yv.w=acc[m][3];
    *(float4*)&Yb[(m0+m)*384 + oc + c0] = yv;
  }
}

// ---------------- split-K temporal attention
__global__ __launch_bounds__(256) void tattn_split_kernel(
    const float* __restrict__ qkv, float* __restrict__ PO,
    float* __restrict__ PM, float* __restrict__ PL)
{
  int b=blockIdx.x, h=blockIdx.y, s=blockIdx.z, tid=threadIdx.x;
  __shared__ float Ksh[32*32];
  __shared__ float Vsh[32*32];
  const float* base = qkv + (size_t)b*256*384;
  int k0 = s*32;
  for(int i=tid;i<1024;i+=256){
    int t=i>>5, d=i&31;
    Ksh[i]=base[(size_t)(k0+t)*384+128+h*32+d];
    Vsh[i]=base[(size_t)(k0+t)*384+256+h*32+d];
  }
  float q[32];
  #pragma unroll
  for(int d=0;d<32;d++) q[d]=base[(size_t)tid*384+h*32+d];
  __syncthreads();
  const float scale=0.17677669529663687f;
  float sc[32];
  float mx=-1e30f;
  #pragma unroll
  for(int k=0;k<32;k++){
    float sv=0.f;
    #pragma unroll
    for(int d=0;d<32;d++) sv += q[d]*Ksh[k*32+d];
    sc[k]=sv*scale;
    mx=fmaxf(mx,sc[k]);
  }
  float l=0.f, o[32];
  #pragma unroll
  for(int d=0;d<32;d++) o[d]=0.f;
  #pragma unroll
  for(int k=0;k<32;k++){
    float p=expf(sc[k]-mx);
    l+=p;
    #pragma unroll
    for(int d=0;d<32;d++) o[d]+=p*Vsh[k*32+d];
  }
  int bh = b*4+h;
  size_t idx = ((size_t)s*64 + bh)*256 + tid;
  PM[idx]=mx; PL[idx]=l;
  float* po = PO + idx*32;
  #pragma unroll
  for(int d=0;d<32;d++) po[d]=o[d];
}

__global__ __launch_bounds__(256) void attn_combine_kernel(
    const float* __restrict__ PO, const float* __restrict__ PM,
    const float* __restrict__ PL, float* __restrict__ obuf)
{
  int tid=threadIdx.x;
  int ql = tid>>5, d = tid&31;
  int bh = blockIdx.x >> 5;
  int qc = blockIdx.x & 31;
  int q = qc*8 + ql;
  float ms[8], ls[8];
  float M=-1e30f;
  #pragma unroll
  for(int s=0;s<8;s++){
    size_t idx = ((size_t)s*64 + bh)*256 + q;
    ms[s]=PM[idx]; ls[s]=PL[idx];
    M=fmaxf(M,ms[s]);
  }
  float L=0.f, ov=0.f;
  #pragma unroll
  for(int s=0;s<8;s++){
    float w = expf(ms[s]-M);
    L += ls[s]*w;
    size_t idx = ((size_t)s*64 + bh)*256 + q;
    ov += w * PO[idx*32 + d];
  }
  int b = bh>>2, h = bh&3;
  obuf[(size_t)(b*256+q)*128 + h*32 + d] = ov / L;
}

// ---------------- fallback monolithic temporal attention
__global__ __launch_bounds__(256) void tattn_kernel(
    const float* __restrict__ qkv, float* __restrict__ obuf)
{
  int b=blockIdx.x, h=blockIdx.y, tid=threadIdx.x;
  __shared__ float Ksh[256*32];
  __shared__ float Vsh[64*32];
  const float* base = qkv + (size_t)b*256*384;
  for(int i=tid;i<8192;i+=256){
    int t=i>>5, d=i&31;
    Ksh[i]=base[t*384+128+h*32+d];
  }
  float q[32];
  #pragma unroll
  for(int d=0;d<32;d++) q[d]=base[(size_t)tid*384+h*32+d];
  __syncthreads();
  const float scale=0.17677669529663687f;
  float mx=-1e30f;
  for(int k=0;k<256;k++){
    float s=0.f;
    #pragma unroll
    for(int d=0;d<32;d++) s += q[d]*Ksh[k*32+d];
    mx=fmaxf(mx,s*scale);
  }
  float l=0.f, o[32];
  #pragma unroll
  for(int d=0;d<32;d++) o[d]=0.f;
  for(int kc=0;kc<256;kc+=64){
    __syncthreads();
    for(int i=tid;i<2048;i+=256){
      int t=i>>5, d=i&31;
      Vsh[i]=base[(size_t)(kc+t)*384+256+h*32+d];
    }
    __syncthreads();
    for(int k2=0;k2<64;k2++){
      float s=0.f;
      #pragma unroll
      for(int d=0;d<32;d++) s += q[d]*Ksh[(kc+k2)*32+d];
      float p=expf(s*scale-mx);
      l+=p;
      #pragma unroll
      for(int d=0;d<32;d++) o[d]+=p*Vsh[k2*32+d];
    }
  }
  float inv=1.f/l;
  float* orow = obuf + (size_t)(b*256+tid)*128 + h*32;
  #pragma unroll
  for(int d=0;d<32;d++) orow[d]=o[d]*inv;
}

// ---------------- temporal out-proj + residual + LN1
__global__ __launch_bounds__(256) void tproj_gemm_kernel(
    const float* __restrict__ O, float* __restrict__ F,
    const float* __restrict__ w, const float* __restrict__ b,
    const float* __restrict__ lg, const float* __restrict__ lb)
{
  __shared__ float Os[32*128];
  __shared__ float Ys[32*128];
  int tid=threadIdx.x;
  const float* Ob = O + (size_t)blockIdx.x*32*128;
  float* Fb = F + (size_t)blockIdx.x*32*128;
  for(int i=tid;i<4096;i+=256) Os[i]=Ob[i];
  __syncthreads();
  int cg = tid & 31, c0 = cg*4;
  int mg = tid >> 5, m0 = mg*4;
  float acc[4][4];
  float4 bv = *(const float4*)&b[c0];
  #pragma unroll
  for(int m=0;m<4;m++){ acc[m][0]=bv.x;acc[m][1]=bv.y;acc[m][2]=bv.z;acc[m][3]=bv.w; }
  for(int k0=0;k0<128;k0+=4){
    float4 w0 = *(const float4*)&w[(k0+0)*128 + c0];
    float4 w1 = *(const float4*)&w[(k0+1)*128 + c0];
    float4 w2 = *(const float4*)&w[(k0+2)*128 + c0];
    float4 w3 = *(const float4*)&w[(k0+3)*128 + c0];
    #pragma unroll
    for(int m=0;m<4;m++){
      float4 xv = *(const float4*)&Os[(m0+m)*128 + k0];
      acc[m][0] += xv.x*w0.x + xv.y*w1.x + xv.z*w2.x + xv.w*w3.x;
      acc[m][1] += xv.x*w0.y + xv.y*w1.y + xv.z*w2.y + xv.w*w3.y;
      acc[m][2] += xv.x*w0.z + xv.y*w1.z + xv.z*w2.z + xv.w*w3.z;
      acc[m][3] += xv.x*w0.w + xv.y*w1.w + xv.z*w2.w + xv.w*w3.w;
    }
  }
  #pragma unroll
  for(int m=0;m<4;m++){
    float4 fv = *(const float4*)&Fb[(m0+m)*128 + c0];
    float4 yv;
    yv.x = fv.x + acc[m][0]; yv.y = fv.y + acc[m][1];
    yv.z = fv.z + acc[m][2]; yv.w = fv.w + acc[m][3];
    *(float4*)&Ys[(m0+m)*128 + c0] = yv;
  }
  __syncthreads();
  int lane = tid & 63, wv = tid >> 6;
  for(int row=wv; row<32; row+=4){
    float e0=Ys[row*128+lane], e1=Ys[row*128+64+lane];
    float mm = wsum64(e0+e1)*(1.f/128.f);
    float d0=e0-mm, d1=e1-mm;
    float rs = rsqrtf(wsum64(d0*d0+d1*d1)*(1.f/128.f)+1e-5f);
    Fb[row*128+lane]    = d0*rs*lg[lane]+lb[lane];
    Fb[row*128+64+lane] = d1*rs*lg[64+lane]+lb[64+lane];
  }
}

// ---------------- Kernel 5: attention pooling over T + classifier
__global__ __launch_bounds__(256) void pool_cls_kernel(
    const float* __restrict__ h2,
    const float* __restrict__ apw,const float* __restrict__ apb,
    const float* __restrict__ c1w,const float* __restrict__ c1b,
    const float* __restrict__ clng,const float* __restrict__ clnb,
    const float* __restrict__ c2w,const float* __restrict__ c2b,
    float* __restrict__ out)
{
  int b=blockIdx.x, tid=threadIdx.x;
  __shared__ float lg[256];
  __shared__ float wt[256];
  __shared__ float invs[1];
  __shared__ float pooled[128];
  __shared__ float z[32];
  const float* H = h2 + (size_t)b*256*128;
  {
    float s=apb[0];
    #pragma unroll
    for(int k=0;k<128;k++) s += H[(size_t)tid*128+k]*apw[k];
    lg[tid]=s;
  }
  __syncthreads();
  if(tid==0){
    float mx=-1e30f;
    for(int i=0;i<256;i++) mx=fmaxf(mx,lg[i]);
    float sm=0.f;
    for(int i=0;i<256;i++){ float e=expf(lg[i]-mx); wt[i]=e; sm+=e; }
    invs[0]=1.f/sm;
  }
  __syncthreads();
  float inv=invs[0];
  if(tid<128){
    float s=0.f;
    for(int t=0;t<256;t++) s += wt[t]*inv*H[(size_t)t*128+tid];
    pooled[tid]=s;
  }
  __syncthreads();
  if(tid<32){
    float s=c1b[tid];
    #pragma unroll
    for(int k=0;k<128;k++) s += pooled[k]*c1w[k*32+tid];
    z[tid]=s;
  }
  __syncthreads();
  if(tid==0){
    float m=0.f;
    for(int i=0;i<32;i++) m+=z[i];
    m *= (1.f/32.f);
    float v=0.f;
    for(int i=0;i<32;i++){ float d=z[i]-m; v+=d*d; }
    v *= (1.f/32.f);
    float rs=rsqrtf(v+1e-5f);
    for(int i=0;i<32;i++) z[i]=fmaxf((z[i]-m)*rs*clng[i]+clnb[i],0.f);
  }
  __syncthreads();
  if(tid<2){
    float s=c2b[tid];
    #pragma unroll
    for(int k=0;k<32;k++) s += z[k]*c2w[k*2+tid];
    out[b*2+tid]=s;
  }
}

extern "C" void kernel_launch(void* const* d_in, const int* in_sizes, int n_in,
                              void* d_out, int out_size, void* d_ws, size_t ws_size,
                              hipStream_t stream) {
  const float* x0 = (const float*)d_in[0];
  const float* x1 = (const float*)d_in[1];
  const float* x2 = (const float*)d_in[2];
  const float* x3 = (const float*)d_in[3];
  const float* x4 = (const float*)d_in[4];
  const float* x5 = (const float*)d_in[5];
  const float* gfeat   = (const float*)d_in[6];
  const float* alpha_p = (const float*)d_in[7];
  const float* g1w = (const float*)d_in[8];
  const float* g1b = (const float*)d_in[9];
  const float* g2w = (const float*)d_in[10];
  const float* g2b = (const float*)d_in[11];
  const float* rlg = (const float*)d_in[12];
  const float* rlb = (const float*)d_in[13];
  const float* spqkvw = (const float*)d_in[14];
  const float* spqkvb = (const float*)d_in[15];
  const float* spow = (const float*)d_in[16];
  const float* spob = (const float*)d_in[17];
  const float* spl1g = (const float*)d_in[18];
  const float* spl1b = (const float*)d_in[19];
  const float* spf1w = (const float*)d_in[20];
  const float* spf1b = (const float*)d_in[21];
  const float* spf2w = (const float*)d_in[22];
  const float* spf2b = (const float*)d_in[23];
  const float* spl2g = (const float*)d_in[24];
  const float* spl2b = (const float*)d_in[25];
  const float* rlogit = (const float*)d_in[26];
  const float* gate1w = (const float*)d_in[27];
  const float* gate1b = (const float*)d_in[28];
  const float* gate2w = (const float*)d_in[29];
  const float* gate2b = (const float*)d_in[30];
  const float* caqkvw = (const float*)d_in[31];
  const float* caqkvb = (const float*)d_in[32];
  const float* caow = (const float*)d_in[33];
  const float* caob = (const float*)d_in[34];
  const float* calng = (const float*)d_in[35];
  const float* calnb = (const float*)d_in[36];
  const float* globw = (const float*)d_in[37];
  const float* globb = (const float*)d_in[38];
  const float* glng = (const float*)d_in[39];
  const float* glnb = (const float*)d_in[40];
  const float* flng = (const float*)d_in[41];
  const float* flnb = (const float*)d_in[42];
  const float* tpqkvw = (const float*)d_in[43];
  const float* tpqkvb = (const float*)d_in[44];
  const float* tpow = (const float*)d_in[45];
  const float* tpob = (const float*)d_in[46];
  const float* tpl1g = (const float*)d_in[47];
  const float* tpl1b = (const float*)d_in[48];
  const float* tpf1w = (const float*)d_in[49];
  const float* tpf1b = (const float*)d_in[50];
  const float* tpf2w = (const float*)d_in[51];
  const float* tpf2b = (const float*)d_in[52];
  const float* tpl2g = (const float*)d_in[53];
  const float* tpl2b = (const float*)d_in[54];
  const float* apw = (const float*)d_in[55];
  const float* apb = (const float*)d_in[56];
  const float* c1w = (const float*)d_in[57];
  const float* c1b = (const float*)d_in[58];
  const float* clng = (const float*)d_in[59];
  const float* clnb = (const float*)d_in[60];
  const float* c2w = (const float*)d_in[61];
  const float* c2b = (const float*)d_in[62];

  float* ws = (float*)d_ws;
  float* tok   = ws;                               // 4096*384
  float* fused = tok   + (size_t)NFRM*384;         // 4096*128
  float* qkv   = fused + (size_t)NFRM*128;         // 4096*384
  float* obuf  = qkv   + (size_t)NFRM*384;         // 4096*128
  float* part  = obuf  + (size_t)NFRM*128;         // partials: 3,145,728 floats
  size_t part_elems = (size_t)2*24576*64;
  unsigned short* pk = (unsigned short*)(part + part_elems);
  unsigned short* sp1h = pk;
  unsigned short* sp1l = sp1h + 131072;
  unsigned short* sp2h = sp1l + 131072;
  unsigned short* sp2l = sp2h + 131072;
  unsigned short* tp1h = sp2l + 131072;
  unsigned short* tp1l = tp1h + 262144;
  unsigned short* tp2h = tp1l + 262144;
  unsigned short* tp2l = tp2h + 262144;
  size_t pack_ushorts = 4*131072 + 4*262144;
  size_t need = ((size_t)NFRM*384 + NFRM*128 + NFRM*384 + NFRM*128 + part_elems)*4
              + pack_ushorts*2;
  bool mfma_ok = (ws_size >= need);

  float* attnPO = (float*)(pk + pack_ushorts);
  float* attnPM = attnPO + (size_t)8*64*256*32;
  float* attnPL = attnPM + (size_t)8*64*256;
  size_t need2 = need + ((size_t)8*64*256*32 + 2*(size_t)8*64*256)*4;
  bool attn_ok = (ws_size >= need2);

  if(mfma_ok){
    pack_all_kernel<<<1536,64,0,stream>>>(spf1w,spf2w,tpf1w,tpf2w,
                                          sp1h,sp1l,sp2h,sp2l,tp1h,tp1l,tp2h,tp2l);
  }

  // gcn: 2 waves/block, F=4 frames/wave -> grid (NFRM/8, 6)
  gcn_kernel<<<dim3(NFRM/8,6),128,0,stream>>>(x0,x1,x2,x3,x4,x5,g1w,g1b,g2w,g2b,rlg,rlb,tok);
  sp_attn_kernel<<<NFRM/4,256,0,stream>>>(tok,spqkvw,spqkvb,spow,spob,spl1g,spl1b);
  if(mfma_ok){
    ffn_mfma_partial<64,2><<<dim3(768,2),256,0,stream>>>(tok,part,sp1h,sp1l,spf1b,sp2h,sp2l);
    fuse_kernel<<<NFRM/4,256,0,stream>>>(tok,part,1,spf2b,spl2g,spl2b,
                                      gfeat,alpha_p,rlogit,gate1w,gate1b,gate2w,gate2b,
                                      caqkvw,caqkvb,caow,caob,calng,calnb,
                                      globw,globb,glng,glnb,flng,flnb,fused);
  } else {
    ffn_ln_kernel<64,32><<<768,256,0,stream>>>(tok,tok,spf1w,spf1b,spf2w,spf2b,spl2g,spl2b);
    fuse_kernel<<<NFRM/4,256,0,stream>>>(tok,part,0,spf2b,spl2g,spl2b,
                                      gfeat,alpha_p,rlogit,gate1w,gate1b,gate2w,gate2b,
                                      caqkvw,caqkvb,caow,caob,calng,calnb,
                                      globw,globb,glng,glnb,flng,flnb,fused);
  }
  tqkv_gemm_kernel<<<dim3(128,3),256,0,stream>>>(fused,qkv,tpqkvw,tpqkvb);
  if(attn_ok){
    tattn_split_kernel<<<dim3(NBATCH,4,8),256,0,stream>>>(qkv,attnPO,attnPM,attnPL);
    attn_combine_kernel<<<64*32,256,0,stream>>>(attnPO,attnPM,attnPL,obuf);
  } else {
    tattn_kernel<<<dim3(NBATCH,4),256,0,stream>>>(qkv,obuf);
  }
  tproj_gemm_kernel<<<128,256,0,stream>>>(obuf,fused,tpow,tpob,tpl1g,tpl1b);
  if(mfma_ok){
    ffn_mfma_partial<128,4><<<dim3(128,4),256,0,stream>>>(fused,part,tp1h,tp1l,tpf1b,tp2h,tp2l);
    ffn_combine_kernel<128,4><<<NFRM/4,256,0,stream>>>(fused,part,obuf,tpf2b,tpl2g,tpl2b);
  } else {
    ffn_ln_kernel<128,16><<<256,256,0,stream>>>(fused,obuf,tpf1w,tpf1b,tpf2w,tpf2b,tpl2g,tpl2b);
  }
  pool_cls_kernel<<<NBATCH,256,0,stream>>>(obuf,apw,apb,c1w,c1b,clng,clnb,c2w,c2b,(float*)d_out);
}

// Round 14
// 340.990 us; speedup vs baseline: 1.1072x; 1.1072x over previous
//
#include <hip/hip_runtime.h>
#include <math.h>
#include <stddef.h>

#define NFRM 4096   // B*T
#define NBATCH 16

typedef __attribute__((ext_vector_type(8))) short short8v;
typedef __attribute__((ext_vector_type(4))) float f32x4;
#define MFMA_BF16(a,b,c) __builtin_amdgcn_mfma_f32_16x16x32_bf16(a,b,c,0,0,0)

__device__ inline float wsum64(float v){
  #pragma unroll
  for(int m=32;m>=1;m>>=1) v += __shfl_xor(v, m, 64);
  return v;
}

__device__ inline float pe_val(int t,int d){
  int k = d >> 1;
  float div = expf(-(float)(2*k) * (9.210340371976184f/128.f));
  float ang = (float)t * div;
  return (d & 1) ? cosf(ang) : sinf(ang);
}

// split x into hi+lo bf16 (round-to-nearest-even)
__device__ inline void bf16split(float x, unsigned short &h, unsigned short &l){
  unsigned u = __float_as_uint(x);
  unsigned r = (u + 0x7FFFu + ((u>>16)&1u)) & 0xFFFF0000u;
  h = (unsigned short)(r>>16);
  float rem = x - __uint_as_float(r);
  unsigned u2 = __float_as_uint(rem);
  unsigned r2 = (u2 + 0x7FFFu + ((u2>>16)&1u));
  l = (unsigned short)(r2>>16);
}

// ---------------- fused pack: all 4 FFN weights into MFMA B-fragment layout (hi/lo bf16)
__global__ __launch_bounds__(64) void pack_all_kernel(
    const float* __restrict__ spf1w, const float* __restrict__ spf2w,
    const float* __restrict__ tpf1w, const float* __restrict__ tpf2w,
    unsigned short* __restrict__ sp1h, unsigned short* __restrict__ sp1l,
    unsigned short* __restrict__ sp2h, unsigned short* __restrict__ sp2l,
    unsigned short* __restrict__ tp1h, unsigned short* __restrict__ tp1l,
    unsigned short* __restrict__ tp2h, unsigned short* __restrict__ tp2l)
{
  int b = blockIdx.x, lane = threadIdx.x;
  const float* w; unsigned short *hi, *lo; int K, N, ntile, s;
  if(b < 256){        w=spf1w; hi=sp1h; lo=sp1l; K=64;   N=2048; ntile=b&127;        s=b>>7; }
  else if(b < 512){   int bb=b-256;  w=spf2w; hi=sp2h; lo=sp2l; K=2048; N=64;   ntile=bb&3;   s=bb>>2; }
  else if(b < 1024){  int bb=b-512;  w=tpf1w; hi=tp1h; lo=tp1l; K=128;  N=2048; ntile=bb&127; s=bb>>7; }
  else {              int bb=b-1024; w=tpf2w; hi=tp2h; lo=tp2l; K=2048; N=128;  ntile=bb&7;   s=bb>>3; }
  int n = ntile*16 + (lane & 15);
  int k0 = s*32 + (lane>>4)*8;
  size_t off = (((size_t)ntile*(K/32) + s)*64 + lane)*8;
  #pragma unroll
  for(int e=0;e<8;e++){
    float v = w[(size_t)(k0+e)*N + n];
    unsigned short h,l;
    bf16split(v,h,l);
    hi[off+e]=h; lo[off+e]=l;
  }
}

// ---------------- MFMA FFN partial: P[s] = relu(X@W1+b1)[:,slice] @ W2[slice,:]
template<int D, int NS>
__global__ __launch_bounds__(256) void ffn_mfma_partial(
    const float* __restrict__ X, float* __restrict__ P,
    const unsigned short* __restrict__ w1h, const unsigned short* __restrict__ w1l,
    const float* __restrict__ b1,
    const unsigned short* __restrict__ w2h, const unsigned short* __restrict__ w2l)
{
  constexpr int TM=32, JC=128;
  constexpr int KS1 = D/32;
  constexpr int NT2W = (D/16)/4;
  constexpr int HS = 2048/NS;
  constexpr int NCH = HS/JC;
  constexpr int HP = JC + 8;
  __shared__ unsigned short Hh[TM][HP];
  __shared__ unsigned short Hl[TM][HP];
  int tid = threadIdx.x;
  int lane = tid & 63, w = tid >> 6;
  int ar = lane & 15, ak = lane >> 4;
  size_t Ntok = (size_t)gridDim.x*TM;
  const float* Xb = X + (size_t)blockIdx.x*TM*D;

  short8v xah[2][KS1], xal[2][KS1];
  #pragma unroll
  for(int mt=0;mt<2;mt++){
    #pragma unroll
    for(int s=0;s<KS1;s++){
      const float* xp = Xb + (size_t)(mt*16+ar)*D + s*32 + ak*8;
      #pragma unroll
      for(int e=0;e<8;e++){
        unsigned short h,l;
        bf16split(xp[e],h,l);
        xah[mt][s][e]=(short)h; xal[mt][s][e]=(short)l;
      }
    }
  }

  f32x4 acc2[2][NT2W];
  #pragma unroll
  for(int mt=0;mt<2;mt++)
    #pragma unroll
    for(int nt=0;nt<NT2W;nt++)
      acc2[mt][nt] = (f32x4){0.f,0.f,0.f,0.f};

  for(int ch=0; ch<NCH; ch++){
    int jc = blockIdx.y*HS + ch*JC;
    f32x4 a1[2][2];
    #pragma unroll
    for(int mt=0;mt<2;mt++){ a1[mt][0]=(f32x4){0,0,0,0}; a1[mt][1]=(f32x4){0,0,0,0}; }
    #pragma unroll
    for(int s=0;s<KS1;s++){
      #pragma unroll
      for(int nt=0;nt<2;nt++){
        int ntile1 = (jc + w*32 + nt*16) >> 4;
        size_t off = (((size_t)ntile1*KS1 + s)*64 + lane)*8;
        short8v bh = *(const short8v*)(w1h + off);
        short8v bl = *(const short8v*)(w1l + off);
        #pragma unroll
        for(int mt=0;mt<2;mt++){
          a1[mt][nt] = MFMA_BF16(xah[mt][s], bh, a1[mt][nt]);
          a1[mt][nt] = MFMA_BF16(xah[mt][s], bl, a1[mt][nt]);
          a1[mt][nt] = MFMA_BF16(xal[mt][s], bh, a1[mt][nt]);
        }
      }
    }
    __syncthreads();
    #pragma unroll
    for(int nt=0;nt<2;nt++){
      int colBase = w*32 + nt*16 + ar;
      float bval = b1[jc + colBase];
      #pragma unroll
      for(int mt=0;mt<2;mt++){
        #pragma unroll
        for(int r=0;r<4;r++){
          float hv = a1[mt][nt][r] + bval;
          hv = fmaxf(hv, 0.f);
          unsigned short h,l;
          bf16split(hv,h,l);
          int row = mt*16 + ak*4 + r;
          Hh[row][colBase]=h; Hl[row][colBase]=l;
        }
      }
    }
    __syncthreads();
    #pragma unroll
    for(int s2=0;s2<4;s2++){
      short8v ah[2], al[2];
      #pragma unroll
      for(int mt=0;mt<2;mt++){
        ah[mt] = *(const short8v*)&Hh[mt*16+ar][s2*32 + ak*8];
        al[mt] = *(const short8v*)&Hl[mt*16+ar][s2*32 + ak*8];
      }
      #pragma unroll
      for(int nt=0;nt<NT2W;nt++){
        int ntile2 = w*NT2W + nt;
        int kstep2 = (jc >> 5) + s2;
        size_t off = (((size_t)ntile2*64 + kstep2)*64 + lane)*8;
        short8v bh = *(const short8v*)(w2h + off);
        short8v bl = *(const short8v*)(w2l + off);
        #pragma unroll
        for(int mt=0;mt<2;mt++){
          acc2[mt][nt] = MFMA_BF16(ah[mt], bh, acc2[mt][nt]);
          acc2[mt][nt] = MFMA_BF16(ah[mt], bl, acc2[mt][nt]);
          acc2[mt][nt] = MFMA_BF16(al[mt], bh, acc2[mt][nt]);
        }
      }
    }
  }
  float* Pb = P + (size_t)blockIdx.y*Ntok*D + (size_t)blockIdx.x*TM*D;
  #pragma unroll
  for(int mt=0;mt<2;mt++){
    #pragma unroll
    for(int nt=0;nt<NT2W;nt++){
      int col = (w*NT2W + nt)*16 + ar;
      #pragma unroll
      for(int r=0;r<4;r++){
        int row = mt*16 + ak*4 + r;
        Pb[(size_t)row*D + col] = acc2[mt][nt][r];
      }
    }
  }
}

// ---------------- combine partials: Y = LN(X + sum_s P_s + b2)  (temporal path)
template<int D, int NS>
__global__ __launch_bounds__(256) void ffn_combine_kernel(
    const float* __restrict__ X, const float* __restrict__ P,
    float* __restrict__ Y,
    const float* __restrict__ b2,
    const float* __restrict__ lg, const float* __restrict__ lb)
{
  constexpr int EPL = D/64;
  int tid=threadIdx.x;
  int lane = tid & 63;
  size_t Ntok = (size_t)gridDim.x*4;
  size_t row = (size_t)blockIdx.x*4 + (tid>>6);
  size_t base = row*D;
  float e[EPL];
  float s=0.f;
  #pragma unroll
  for(int i=0;i<EPL;i++){
    int c = i*64+lane;
    float v = X[base+c] + b2[c];
    #pragma unroll
    for(int sp=0;sp<NS;sp++) v += P[(size_t)sp*Ntok*D + base + c];
    e[i]=v; s+=v;
  }
  float mm = wsum64(s)*(1.f/D);
  float s2=0.f;
  #pragma unroll
  for(int i=0;i<EPL;i++){ float d=e[i]-mm; s2+=d*d; }
  float rs = rsqrtf(wsum64(s2)*(1.f/D)+1e-5f);
  #pragma unroll
  for(int i=0;i<EPL;i++){
    int c=i*64+lane;
    Y[base+c] = (e[i]-mm)*rs*lg[c]+lb[c];
  }
}

// ---------------- Kernel 1: GCN — wave-synchronous runtime-n body (round-12 proven), F=4 frames/wave
__global__ __launch_bounds__(128) void gcn_kernel(
    const float* __restrict__ x0,const float* __restrict__ x1,
    const float* __restrict__ x2,const float* __restrict__ x3,
    const float* __restrict__ x4,const float* __restrict__ x5,
    const float* __restrict__ g1w,const float* __restrict__ g1b,
    const float* __restrict__ g2w,const float* __restrict__ g2b,
    const float* __restrict__ rg,const float* __restrict__ rb,
    float* __restrict__ tok)
{
  const int F = 4;
  int tid=threadIdx.x;
  int lane = tid & 63, w = tid >> 6;
  int f0 = (blockIdx.x*2 + w)*F;
  int r = blockIdx.y;
  int n = (r==5) ? 20 : ((r==2 || r==3) ? 11 : 9);
  const float* xr = (r==0)?x0:(r==1)?x1:(r==2)?x2:(r==3)?x3:(r==4)?x4:x5;
  int c = lane & 31;

  __shared__ float xs[2][20*12];      // stride-12 padded (f4-aligned)
  __shared__ float t0g[2][24*32];     // rows 0,1 and n+2,n+3 are zero guards
  __shared__ float t1s[2][20*32];
  __shared__ float Cw[2][20][5];      // per-wave adjacency coefs

  // fixed per-wave setup (amortized over F frames)
  float W1c[11], W2c[32];
  #pragma unroll
  for(int k=0;k<11;k++) W1c[k]=g1w[r*352 + k*32 + c];
  #pragma unroll
  for(int k=0;k<32;k++) W2c[k]=g2w[r*1024 + k*32 + c];
  float b1c = g1b[r*32+c], b2c = g2b[r*32+c];
  float rgv = rg[r*64+lane], rbv = rb[r*64+lane];

  for(int i=lane;i<100;i+=64){
    int node=i/5, j=i%5, m=node+j-2;
    float cf=0.f;
    if(node<n && m>=0 && m<n){
      int di = 1 + min(node,2) + min(n-1-node,2);
      int dm = 1 + min(m,2) + min(n-1-m,2);
      cf = rsqrtf((float)(di*dm));
    }
    Cw[w][node][j]=cf;
  }
  for(int i=lane;i<128;i+=64){
    int row4=i>>5, col=i&31;
    int row = (row4<2) ? row4 : (n+row4);
    t0g[w][row*32+col]=0.f;
  }

  for(int it=0; it<F; it++){
    int f = f0 + it;
    for(int i=lane;i<n*12;i+=64){
      int node=i/12, k=i-node*12;
      xs[w][i] = (k<11) ? xr[(size_t)f*n*11 + node*11 + k] : 0.f;
    }
    __builtin_amdgcn_wave_barrier();
    for(int i=lane;i<n*32;i+=64){
      int node=i>>5;
      float4 xa = *(const float4*)&xs[w][node*12];
      float4 xb = *(const float4*)&xs[w][node*12+4];
      float4 xc = *(const float4*)&xs[w][node*12+8];
      float s = xa.x*W1c[0]+xa.y*W1c[1]+xa.z*W1c[2]+xa.w*W1c[3]
              + xb.x*W1c[4]+xb.y*W1c[5]+xb.z*W1c[6]+xb.w*W1c[7]
              + xc.x*W1c[8]+xc.y*W1c[9]+xc.z*W1c[10];
      t0g[w][(node+2)*32+c]=s;
    }
    __builtin_amdgcn_wave_barrier();
    for(int i=lane;i<n*32;i+=64){
      int node=i>>5;
      float s=b1c;
      #pragma unroll
      for(int j=0;j<5;j++) s += Cw[w][node][j]*t0g[w][(node+j)*32+c];
      t1s[w][i]=fmaxf(s,0.f);
    }
    __builtin_amdgcn_wave_barrier();
    for(int i=lane;i<n*32;i+=64){
      int node=i>>5;
      float s=0.f;
      #pragma unroll
      for(int k0=0;k0<32;k0+=4){
        float4 tv = *(const float4*)&t1s[w][node*32+k0];
        s += tv.x*W2c[k0] + tv.y*W2c[k0+1] + tv.z*W2c[k0+2] + tv.w*W2c[k0+3];
      }
      t0g[w][(node+2)*32+c]=s;
    }
    __builtin_amdgcn_wave_barrier();
    for(int i=lane;i<n*32;i+=64){
      int node=i>>5;
      float s=b2c;
      #pragma unroll
      for(int j=0;j<5;j++) s += Cw[w][node][j]*t0g[w][(node+j)*32+c];
      t1s[w][i]=fmaxf(s,0.f);
    }
    __builtin_amdgcn_wave_barrier();
    float v;
    if(lane<32){
      float s=0.f;
      for(int m=0;m<n;m++) s += t1s[w][m*32+lane];
      v = s/(float)n;
    } else {
      float mx=-1e30f;
      for(int m=0;m<n;m++) mx = fmaxf(mx, t1s[w][m*32+c]);
      v = mx;
    }
    float m1 = wsum64(v)*(1.f/64.f);
    float d1 = v - m1;
    float var = wsum64(d1*d1)*(1.f/64.f);
    float y = d1*rsqrtf(var+1e-5f)*rgv + rbv;
    tok[((size_t)f*6+r)*64+lane] = y;
    __builtin_amdgcn_wave_barrier();
  }
}

// ---------------- Kernel 2a: spatial attention + residual + LN1 — 4 frames/block, block-wide GEMMs
__global__ __launch_bounds__(256) void sp_attn_kernel(
    float* __restrict__ tok,
    const float* __restrict__ qkvw,const float* __restrict__ qkvb,
    const float* __restrict__ ow,const float* __restrict__ ob,
    const float* __restrict__ l1g,const float* __restrict__ l1b)
{
  __shared__ float Xs[24][64];
  __shared__ float QKV[24][192];
  __shared__ float SC[4][144];
  __shared__ float AO[24][64];
  int tid=threadIdx.x;
  int f0 = blockIdx.x*4;
  float* Xf = &Xs[0][0];
  for(int i=tid;i<1536;i+=256) Xf[i] = tok[(size_t)f0*384 + i];
  __syncthreads();
  {
    int cg = tid & 31, c0 = cg*6;
    int rg = tid >> 5, r0 = rg*3;
    float acc[3][6];
    #pragma unroll
    for(int m=0;m<3;m++)
      #pragma unroll
      for(int j=0;j<6;j++) acc[m][j]=qkvb[c0+j];
    for(int k=0;k<64;k++){
      float wv[6];
      #pragma unroll
      for(int j=0;j<6;j++) wv[j]=qkvw[k*192+c0+j];
      float xv0=Xs[r0][k], xv1=Xs[r0+1][k], xv2=Xs[r0+2][k];
      #pragma unroll
      for(int j=0;j<6;j++){
        acc[0][j]+=xv0*wv[j];
        acc[1][j]+=xv1*wv[j];
        acc[2][j]+=xv2*wv[j];
      }
    }
    #pragma unroll
    for(int m=0;m<3;m++)
      #pragma unroll
      for(int j=0;j<6;j++) QKV[r0+m][c0+j]=acc[m][j];
  }
  __syncthreads();
  for(int i=tid;i<576;i+=256){
    int fr=i/144, rest=i%144;
    int h=rest/36, qi=(rest%36)/6, ki=rest%6;
    float s=0.f;
    #pragma unroll
    for(int d=0;d<16;d++) s += QKV[fr*6+qi][h*16+d]*QKV[fr*6+ki][64+h*16+d];
    SC[fr][rest]=s*0.25f;
  }
  __syncthreads();
  if(tid<96){
    int fr=tid/24, idx=tid%24;
    int base=idx*6;
    float mx=-1e30f;
    for(int k=0;k<6;k++) mx=fmaxf(mx,SC[fr][base+k]);
    float sm=0.f;
    for(int k=0;k<6;k++){ float e=expf(SC[fr][base+k]-mx); SC[fr][base+k]=e; sm+=e; }
    float rr=1.f/sm;
    for(int k=0;k<6;k++) SC[fr][base+k]*=rr;
  }
  __syncthreads();
  for(int i=tid;i<1536;i+=256){
    int fr=i/384, rem=i%384;
    int row=rem/64, c=rem&63, h=c/16;
    float s=0.f;
    #pragma unroll
    for(int k=0;k<6;k++) s += SC[fr][h*36+row*6+k]*QKV[fr*6+k][128+c];
    AO[fr*6+row][c]=s;
  }
  __syncthreads();
  {
    int cg = tid & 31, c0 = cg*2;
    int rg = tid >> 5, r0 = rg*3;
    float acc[3][2];
    #pragma unroll
    for(int m=0;m<3;m++){ acc[m][0]=ob[c0]; acc[m][1]=ob[c0+1]; }
    for(int k=0;k<64;k++){
      float w0=ow[k*64+c0], w1=ow[k*64+c0+1];
      float a0=AO[r0][k], a1=AO[r0+1][k], a2=AO[r0+2][k];
      acc[0][0]+=a0*w0; acc[0][1]+=a0*w1;
      acc[1][0]+=a1*w0; acc[1][1]+=a1*w1;
      acc[2][0]+=a2*w0; acc[2][1]+=a2*w1;
    }
    #pragma unroll
    for(int m=0;m<3;m++){
      QKV[r0+m][c0]   = Xs[r0+m][c0]   + acc[m][0];
      QKV[r0+m][c0+1] = Xs[r0+m][c0+1] + acc[m][1];
    }
  }
  __syncthreads();
  {
    int lane = tid & 63, w = tid >> 6;
    #pragma unroll
    for(int rr=0;rr<6;rr++){
      int row = w*6+rr;
      float v=QKV[row][lane];
      float mm=wsum64(v)*(1.f/64.f);
      float d=v-mm;
      float var=wsum64(d*d)*(1.f/64.f);
      tok[(size_t)f0*384 + row*64 + lane]=d*rsqrtf(var+1e-5f)*l1g[lane]+l1b[lane];
    }
  }
}

// ---------------- fused fp32 FFN + residual + LN (fallback path)
template<int D, int TM>
__global__ __launch_bounds__(256) void ffn_ln_kernel(
    const float* __restrict__ X, float* __restrict__ Yout,
    const float* __restrict__ w1,const float* __restrict__ b1,
    const float* __restrict__ w2,const float* __restrict__ b2,
    const float* __restrict__ lg,const float* __restrict__ lb)
{
  constexpr int JC = 128;
  constexpr int JS = JC + 4;
  constexpr int M1 = TM/8;
  constexpr int CG = D/4;
  constexpr int MG2 = 256/CG;
  constexpr int M2 = TM/MG2;
  __shared__ float Xs[TM*D];
  __shared__ float Hs[TM*JS];
  int tid=threadIdx.x;
  const float* Xb = X + (size_t)blockIdx.x*TM*D;
  for(int i=tid;i<TM*D;i+=256) Xs[i]=Xb[i];

  int jg = tid & 31, j0 = jg*4;
  int mg1 = tid >> 5;
  int m10 = mg1*M1;
  int cg = tid % CG, c0 = cg*4;
  int mg2 = tid / CG;
  int m20 = mg2*M2;

  float acc[M2][4];
  #pragma unroll
  for(int m=0;m<M2;m++){ acc[m][0]=0.f;acc[m][1]=0.f;acc[m][2]=0.f;acc[m][3]=0.f; }

  __syncthreads();
  for(int jc=0;jc<2048;jc+=JC){
    float a1[M1][4];
    float4 bv = *(const float4*)&b1[jc+j0];
    #pragma unroll
    for(int m=0;m<M1;m++){ a1[m][0]=bv.x;a1[m][1]=bv.y;a1[m][2]=bv.z;a1[m][3]=bv.w; }
    for(int k0=0;k0<D;k0+=4){
      float4 wr0 = *(const float4*)&w1[(size_t)(k0+0)*2048 + jc + j0];
      float4 wr1 = *(const float4*)&w1[(size_t)(k0+1)*2048 + jc + j0];
      float4 wr2 = *(const float4*)&w1[(size_t)(k0+2)*2048 + jc + j0];
      float4 wr3 = *(const float4*)&w1[(size_t)(k0+3)*2048 + jc + j0];
      #pragma unroll
      for(int m=0;m<M1;m++){
        float4 xv = *(const float4*)&Xs[(m10+m)*D + k0];
        a1[m][0] += xv.x*wr0.x + xv.y*wr1.x + xv.z*wr2.x + xv.w*wr3.x;
        a1[m][1] += xv.x*wr0.y + xv.y*wr1.y + xv.z*wr2.y + xv.w*wr3.y;
        a1[m][2] += xv.x*wr0.z + xv.y*wr1.z + xv.z*wr2.z + xv.w*wr3.z;
        a1[m][3] += xv.x*wr0.w + xv.y*wr1.w + xv.z*wr2.w + xv.w*wr3.w;
      }
    }
    #pragma unroll
    for(int m=0;m<M1;m++){
      float4 hv;
      hv.x=fmaxf(a1[m][0],0.f); hv.y=fmaxf(a1[m][1],0.f);
      hv.z=fmaxf(a1[m][2],0.f); hv.w=fmaxf(a1[m][3],0.f);
      *(float4*)&Hs[(m10+m)*JS + j0] = hv;
    }
    __syncthreads();
    for(int jj0=0;jj0<JC;jj0+=4){
      float4 w20 = *(const float4*)&w2[(size_t)(jc+jj0+0)*D + c0];
      float4 w21 = *(const float4*)&w2[(size_t)(jc+jj0+1)*D + c0];
      float4 w22 = *(const float4*)&w2[(size_t)(jc+jj0+2)*D + c0];
      float4 w23 = *(const float4*)&w2[(size_t)(jc+jj0+3)*D + c0];
      #pragma unroll
      for(int m=0;m<M2;m++){
        float4 hv = *(const float4*)&Hs[(m20+m)*JS + jj0];
        acc[m][0] += hv.x*w20.x + hv.y*w21.x + hv.z*w22.x + hv.w*w23.x;
        acc[m][1] += hv.x*w20.y + hv.y*w21.y + hv.z*w22.y + hv.w*w23.y;
        acc[m][2] += hv.x*w20.z + hv.y*w21.z + hv.z*w22.z + hv.w*w23.z;
        acc[m][3] += hv.x*w20.w + hv.y*w21.w + hv.z*w22.w + hv.w*w23.w;
      }
    }
    __syncthreads();
  }
  {
    float4 b2v = *(const float4*)&b2[c0];
    #pragma unroll
    for(int m=0;m<M2;m++){
      int row = m20+m;
      float4 xv = *(const float4*)&Xs[row*D + c0];
      float4 yv;
      yv.x = xv.x + acc[m][0] + b2v.x;
      yv.y = xv.y + acc[m][1] + b2v.y;
      yv.z = xv.z + acc[m][2] + b2v.z;
      yv.w = xv.w + acc[m][3] + b2v.w;
      *(float4*)&Hs[row*D + c0] = yv;
    }
  }
  __syncthreads();
  constexpr int EPL = D/64;
  int lane = tid & 63, wv = tid >> 6;
  float* Yb = Yout + (size_t)blockIdx.x*TM*D;
  for(int row=wv; row<TM; row+=4){
    float e[EPL];
    float s=0.f;
    #pragma unroll
    for(int i=0;i<EPL;i++){ e[i]=Hs[row*D + i*64 + lane]; s+=e[i]; }
    float mm = wsum64(s)*(1.f/D);
    float s2=0.f;
    #pragma unroll
    for(int i=0;i<EPL;i++){ float d=e[i]-mm; s2+=d*d; }
    float rs = rsqrtf(wsum64(s2)*(1.f/D)+1e-5f);
    #pragma unroll
    for(int i=0;i<EPL;i++)
      Yb[row*D + i*64 + lane] = (e[i]-mm)*rs*lg[i*64+lane]+lb[i*64+lane];
  }
}

// ---------------- Kernel 3: fuse — 4 frames/block; inlines spatial FFN combine (partials+b2+LN2)
__global__ __launch_bounds__(256) void fuse_kernel(
    const float* __restrict__ tok, const float* __restrict__ part, int do_combine,
    const float* __restrict__ sb2, const float* __restrict__ sl2g, const float* __restrict__ sl2b,
    const float* __restrict__ gfeat,
    const float* __restrict__ alpha_p, const float* __restrict__ rlogit,
    const float* __restrict__ g1w,const float* __restrict__ g1b,
    const float* __restrict__ g2w,const float* __restrict__ g2b,
    const float* __restrict__ caqw,const float* __restrict__ caqb,
    const float* __restrict__ caow,const float* __restrict__ caob,
    const float* __restrict__ calng,const float* __restrict__ calnb,
    const float* __restrict__ gw,const float* __restrict__ gb,
    const float* __restrict__ glng,const float* __restrict__ glnb,
    const float* __restrict__ flng,const float* __restrict__ flnb,
    float* __restrict__ fused)
{
  int tid=threadIdx.x;
  int lane = tid & 63, w = tid >> 6;
  int f = blockIdx.x*4 + w;
  __shared__ float X[4][384];
  __shared__ float G1[4][192];
  __shared__ float gt[4][6];
  __shared__ float qv[4][64];
  __shared__ float Qs[4][64];
  __shared__ float KK[4][384], VV[4][384];
  __shared__ float sc[4][24];
  __shared__ float AOs[4][64];

  const float* trow = tok + (size_t)f*384;
  if(do_combine){
    #pragma unroll
    for(int row=0;row<6;row++){
      size_t grow = (size_t)f*6 + row;
      float v = trow[row*64+lane] + sb2[lane]
              + part[grow*64 + lane]
              + part[(size_t)24576*64 + grow*64 + lane];
      float mm = wsum64(v)*(1.f/64.f);
      float d = v-mm;
      float var = wsum64(d*d)*(1.f/64.f);
      X[w][row*64+lane] = d*rsqrtf(var+1e-5f)*sl2g[lane]+sl2b[lane];
    }
  } else {
    for(int i=lane;i<384;i+=64) X[w][i]=trow[i];
  }
  __syncthreads();
  for(int i=lane;i<192;i+=64){
    int rr=i/32, j=i%32;
    float s=g1b[j];
    #pragma unroll
    for(int k=0;k<64;k++) s += X[w][rr*64+k]*g1w[k*32+j];
    G1[w][i]=fmaxf(s,0.f);
  }
  __syncthreads();
  if(lane<6){
    float s=g2b[0];
    #pragma unroll
    for(int k=0;k<32;k++) s += G1[w][lane*32+k]*g2w[k];
    float gate = 1.f/(1.f+expf(-s));
    float rw = log1pf(expf(rlogit[lane]));
    gt[w][lane]=gate*rw;
  }
  __syncthreads();
  for(int i=lane;i<384;i+=64) X[w][i]*=gt[w][i/64];
  __syncthreads();
  {
    float s=0.f;
    #pragma unroll
    for(int rr=0;rr<6;rr++) s+=X[w][rr*64+lane];
    qv[w][lane]=s*(1.f/6.f);
  }
  __syncthreads();
  {
    float s=caqb[lane];
    #pragma unroll
    for(int k=0;k<64;k++) s += qv[w][k]*caqw[k*192+lane];
    Qs[w][lane]=s;
  }
  for(int i=lane;i<384;i+=64){
    int rr=i/64, c=i%64;
    float sk=caqb[64+c], sv=caqb[128+c];
    #pragma unroll
    for(int k=0;k<64;k++){
      float xv=X[w][rr*64+k];
      sk += xv*caqw[k*192+64+c];
      sv += xv*caqw[k*192+128+c];
    }
    KK[w][i]=sk; VV[w][i]=sv;
  }
  __syncthreads();
  if(lane<24){
    int h=lane/6, ki=lane%6;
    float s=0.f;
    #pragma unroll
    for(int d=0;d<16;d++) s += Qs[w][h*16+d]*KK[w][ki*64+h*16+d];
    sc[w][lane]=s*0.25f;
  }
  __syncthreads();
  if(lane<4){
    float mx=-1e30f;
    for(int k=0;k<6;k++) mx=fmaxf(mx,sc[w][lane*6+k]);
    float sm=0.f;
    for(int k=0;k<6;k++){ float e=expf(sc[w][lane*6+k]-mx); sc[w][lane*6+k]=e; sm+=e; }
    float rr=1.f/sm;
    for(int k=0;k<6;k++) sc[w][lane*6+k]*=rr;
  }
  __syncthreads();
  {
    int h=lane/16;
    float s=0.f;
    #pragma unroll
    for(int k=0;k<6;k++) s += sc[w][h*6+k]*VV[w][k*64+lane];
    AOs[w][lane]=s;
  }
  __syncthreads();
  float pr;
  {
    float s=caob[lane];
    #pragma unroll
    for(int k=0;k<64;k++) s += AOs[w][k]*caow[k*64+lane];
    pr = qv[w][lane] + s;
  }
  float m1=wsum64(pr)*(1.f/64.f);
  float d1=pr-m1;
  float v1=wsum64(d1*d1)*(1.f/64.f);
  float fr = d1*rsqrtf(v1+1e-5f)*calng[lane]+calnb[lane];
  float gvv;
  {
    float s=gb[lane];
    #pragma unroll
    for(int k=0;k<4;k++) s += gfeat[(size_t)f*4+k]*gw[k*64+lane];
    gvv=s;
  }
  float m2=wsum64(gvv)*(1.f/64.f);
  float d2=gvv-m2;
  float v2=wsum64(d2*d2)*(1.f/64.f);
  float gg = fmaxf(d2*rsqrtf(v2+1e-5f)*glng[lane]+glnb[lane],0.f)*tanhf(alpha_p[0]);
  float sm_ = wsum64(fr+gg)*(1.f/128.f);
  float da=fr-sm_, db=gg-sm_;
  float vv = wsum64(da*da+db*db)*(1.f/128.f);
  float rs = rsqrtf(vv+1e-5f);
  int t = f & 255;
  fused[(size_t)f*128+lane]     = da*rs*flng[lane]+flnb[lane]         + pe_val(t,lane);
  fused[(size_t)f*128+64+lane]  = db*rs*flng[64+lane]+flnb[64+lane]   + pe_val(t,64+lane);
}

// ---------------- temporal QKV: Y = X@W + b  (grid (128, 3): oc chunk per blockIdx.y)
__global__ __launch_bounds__(256) void tqkv_gemm_kernel(
    const float* __restrict__ X, float* __restrict__ Y,
    const float* __restrict__ w, const float* __restrict__ b)
{
  __shared__ float Xs[32*128];
  int tid=threadIdx.x;
  const float* Xb = X + (size_t)blockIdx.x*32*128;
  for(int i=tid;i<4096;i+=256) Xs[i]=Xb[i];
  __syncthreads();
  int cg = tid & 31, c0 = cg*4;
  int mg = tid >> 5, m0 = mg*4;
  float* Yb = Y + (size_t)blockIdx.x*32*384;
  int oc = blockIdx.y*128;
  float acc[4][4];
  float4 bv = *(const float4*)&b[oc+c0];
  #pragma unroll
  for(int m=0;m<4;m++){ acc[m][0]=bv.x;acc[m][1]=bv.y;acc[m][2]=bv.z;acc[m][3]=bv.w; }
  for(int k0=0;k0<128;k0+=4){
    float4 w0 = *(const float4*)&w[(k0+0)*384 + oc + c0];
    float4 w1 = *(const float4*)&w[(k0+1)*384 + oc + c0];
    float4 w2 = *(const float4*)&w[(k0+2)*384 + oc + c0];
    float4 w3 = *(const float4*)&w[(k0+3)*384 + oc + c0];
    #pragma unroll
    for(int m=0;m<4;m++){
      float4 xv = *(const float4*)&Xs[(m0+m)*128 + k0];
      acc[m][0] += xv.x*w0.x + xv.y*w1.x + xv.z*w2.x + xv.w*w3.x;
      acc[m][1] += xv.x*w0.y + xv.y*w1.y + xv.z*w2.y + xv.w*w3.y;
      acc[m][2] += xv.x*w0.z + xv.y*w1.z + xv.z*w2.z + xv.w*w3.z;
      acc[m][3] += xv.x*w0.w + xv.y*w1.w + xv.z*w2.w + xv.w*w3.w;
    }
  }
  #pragma unroll
  for(int m=0;m<4;m++){
    float4 yv; yv.x=acc[m][0];yv.y=acc[m][1];yv.z=acc[m][2];yv.w=acc[m][3];
    *(float4*)&Yb[(m0+m)*384 + oc + c0] = yv;
  }
}

// ---------------- split-K temporal attention
__global__ __launch_bounds__(256) void tattn_split_kernel(
    const float* __restrict__ qkv, float* __restrict__ PO,
    float* __restrict__ PM, float* __restrict__ PL)
{
  int b=blockIdx.x, h=blockIdx.y, s=blockIdx.z, tid=threadIdx.x;
  __shared__ float Ksh[32*32];
  __shared__ float Vsh[32*32];
  const float* base = qkv + (size_t)b*256*384;
  int k0 = s*32;
  for(int i=tid;i<1024;i+=256){
    int t=i>>5, d=i&31;
    Ksh[i]=base[(size_t)(k0+t)*384+128+h*32+d];
    Vsh[i]=base[(size_t)(k0+t)*384+256+h*32+d];
  }
  float q[32];
  #pragma unroll
  for(int d=0;d<32;d++) q[d]=base[(size_t)tid*384+h*32+d];
  __syncthreads();
  const float scale=0.17677669529663687f;
  float sc[32];
  float mx=-1e30f;
  #pragma unroll
  for(int k=0;k<32;k++){
    float sv=0.f;
    #pragma unroll
    for(int d=0;d<32;d++) sv += q[d]*Ksh[k*32+d];
    sc[k]=sv*scale;
    mx=fmaxf(mx,sc[k]);
  }
  float l=0.f, o[32];
  #pragma unroll
  for(int d=0;d<32;d++) o[d]=0.f;
  #pragma unroll
  for(int k=0;k<32;k++){
    float p=expf(sc[k]-mx);
    l+=p;
    #pragma unroll
    for(int d=0;d<32;d++) o[d]+=p*Vsh[k*32+d];
  }
  int bh = b*4+h;
  size_t idx = ((size_t)s*64 + bh)*256 + tid;
  PM[idx]=mx; PL[idx]=l;
  float* po = PO + idx*32;
  #pragma unroll
  for(int d=0;d<32;d++) po[d]=o[d];
}

__global__ __launch_bounds__(256) void attn_combine_kernel(
    const float* __restrict__ PO, const float* __restrict__ PM,
    const float* __restrict__ PL, float* __restrict__ obuf)
{
  int tid=threadIdx.x;
  int ql = tid>>5, d = tid&31;
  int bh = blockIdx.x >> 5;
  int qc = blockIdx.x & 31;
  int q = qc*8 + ql;
  float ms[8], ls[8];
  float M=-1e30f;
  #pragma unroll
  for(int s=0;s<8;s++){
    size_t idx = ((size_t)s*64 + bh)*256 + q;
    ms[s]=PM[idx]; ls[s]=PL[idx];
    M=fmaxf(M,ms[s]);
  }
  float L=0.f, ov=0.f;
  #pragma unroll
  for(int s=0;s<8;s++){
    float w = expf(ms[s]-M);
    L += ls[s]*w;
    size_t idx = ((size_t)s*64 + bh)*256 + q;
    ov += w * PO[idx*32 + d];
  }
  int b = bh>>2, h = bh&3;
  obuf[(size_t)(b*256+q)*128 + h*32 + d] = ov / L;
}

// ---------------- fallback monolithic temporal attention
__global__ __launch_bounds__(256) void tattn_kernel(
    const float* __restrict__ qkv, float* __restrict__ obuf)
{
  int b=blockIdx.x, h=blockIdx.y, tid=threadIdx.x;
  __shared__ float Ksh[256*32];
  __shared__ float Vsh[64*32];
  const float* base = qkv + (size_t)b*256*384;
  for(int i=tid;i<8192;i+=256){
    int t=i>>5, d=i&31;
    Ksh[i]=base[t*384+128+h*32+d];
  }
  float q[32];
  #pragma unroll
  for(int d=0;d<32;d++) q[d]=base[(size_t)tid*384+h*32+d];
  __syncthreads();
  const float scale=0.17677669529663687f;
  float mx=-1e30f;
  for(int k=0;k<256;k++){
    float s=0.f;
    #pragma unroll
    for(int d=0;d<32;d++) s += q[d]*Ksh[k*32+d];
    mx=fmaxf(mx,s*scale);
  }
  float l=0.f, o[32];
  #pragma unroll
  for(int d=0;d<32;d++) o[d]=0.f;
  for(int kc=0;kc<256;kc+=64){
    __syncthreads();
    for(int i=tid;i<2048;i+=256){
      int t=i>>5, d=i&31;
      Vsh[i]=base[(size_t)(kc+t)*384+256+h*32+d];
    }
    __syncthreads();
    for(int k2=0;k2<64;k2++){
      float s=0.f;
      #pragma unroll
      for(int d=0;d<32;d++) s += q[d]*Ksh[(kc+k2)*32+d];
      float p=expf(s*scale-mx);
      l+=p;
      #pragma unroll
      for(int d=0;d<32;d++) o[d]+=p*Vsh[k2*32+d];
    }
  }
  float inv=1.f/l;
  float* orow = obuf + (size_t)(b*256+tid)*128 + h*32;
  #pragma unroll
  for(int d=0;d<32;d++) orow[d]=o[d]*inv;
}

// ---------------- temporal out-proj + residual + LN1
__global__ __launch_bounds__(256) void tproj_gemm_kernel(
    const float* __restrict__ O, float* __restrict__ F,
    const float* __restrict__ w, const float* __restrict__ b,
    const float* __restrict__ lg, const float* __restrict__ lb)
{
  __shared__ float Os[32*128];
  __shared__ float Ys[32*128];
  int tid=threadIdx.x;
  const float* Ob = O + (size_t)blockIdx.x*32*128;
  float* Fb = F + (size_t)blockIdx.x*32*128;
  for(int i=tid;i<4096;i+=256) Os[i]=Ob[i];
  __syncthreads();
  int cg = tid & 31, c0 = cg*4;
  int mg = tid >> 5, m0 = mg*4;
  float acc[4][4];
  float4 bv = *(const float4*)&b[c0];
  #pragma unroll
  for(int m=0;m<4;m++){ acc[m][0]=bv.x;acc[m][1]=bv.y;acc[m][2]=bv.z;acc[m][3]=bv.w; }
  for(int k0=0;k0<128;k0+=4){
    float4 w0 = *(const float4*)&w[(k0+0)*128 + c0];
    float4 w1 = *(const float4*)&w[(k0+1)*128 + c0];
    float4 w2 = *(const float4*)&w[(k0+2)*128 + c0];
    float4 w3 = *(const float4*)&w[(k0+3)*128 + c0];
    #pragma unroll
    for(int m=0;m<4;m++){
      float4 xv = *(const float4*)&Os[(m0+m)*128 + k0];
      acc[m][0] += xv.x*w0.x + xv.y*w1.x + xv.z*w2.x + xv.w*w3.x;
      acc[m][1] += xv.x*w0.y + xv.y*w1.y + xv.z*w2.y + xv.w*w3.y;
      acc[m][2] += xv.x*w0.z + xv.y*w1.z + xv.z*w2.z + xv.w*w3.z;
      acc[m][3] += xv.x*w0.w + xv.y*w1.w + xv.z*w2.w + xv.w*w3.w;
    }
  }
  #pragma unroll
  for(int m=0;m<4;m++){
    float4 fv = *(const float4*)&Fb[(m0+m)*128 + c0];
    float4 yv;
    yv.x = fv.x + acc[m][0]; yv.y = fv.y + acc[m][1];
    yv.z = fv.z + acc[m][2]; yv.w = fv.w + acc[m][3];
    *(float4*)&Ys[(m0+m)*128 + c0] = yv;
  }
  __syncthreads();
  int lane = tid & 63, wv = tid >> 6;
  for(int row=wv; row<32; row+=4){
    float e0=Ys[row*128+lane], e1=Ys[row*128+64+lane];
    float mm = wsum64(e0+e1)*(1.f/128.f);
    float d0=e0-mm, d1=e1-mm;
    float rs = rsqrtf(wsum64(d0*d0+d1*d1)*(1.f/128.f)+1e-5f);
    Fb[row*128+lane]    = d0*rs*lg[lane]+lb[lane];
    Fb[row*128+64+lane] = d1*rs*lg[64+lane]+lb[64+lane];
  }
}

// ---------------- Kernel 5: attention pooling over T + classifier
__global__ __launch_bounds__(256) void pool_cls_kernel(
    const float* __restrict__ h2,
    const float* __restrict__ apw,const float* __restrict__ apb,
    const float* __restrict__ c1w,const float* __restrict__ c1b,
    const float* __restrict__ clng,const float* __restrict__ clnb,
    const float* __restrict__ c2w,const float* __restrict__ c2b,
    float* __restrict__ out)
{
  int b=blockIdx.x, tid=threadIdx.x;
  __shared__ float lg[256];
  __shared__ float wt[256];
  __shared__ float invs[1];
  __shared__ float pooled[128];
  __shared__ float z[32];
  const float* H = h2 + (size_t)b*256*128;
  {
    float s=apb[0];
    #pragma unroll
    for(int k=0;k<128;k++) s += H[(size_t)tid*128+k]*apw[k];
    lg[tid]=s;
  }
  __syncthreads();
  if(tid==0){
    float mx=-1e30f;
    for(int i=0;i<256;i++) mx=fmaxf(mx,lg[i]);
    float sm=0.f;
    for(int i=0;i<256;i++){ float e=expf(lg[i]-mx); wt[i]=e; sm+=e; }
    invs[0]=1.f/sm;
  }
  __syncthreads();
  float inv=invs[0];
  if(tid<128){
    float s=0.f;
    for(int t=0;t<256;t++) s += wt[t]*inv*H[(size_t)t*128+tid];
    pooled[tid]=s;
  }
  __syncthreads();
  if(tid<32){
    float s=c1b[tid];
    #pragma unroll
    for(int k=0;k<128;k++) s += pooled[k]*c1w[k*32+tid];
    z[tid]=s;
  }
  __syncthreads();
  if(tid==0){
    float m=0.f;
    for(int i=0;i<32;i++) m+=z[i];
    m *= (1.f/32.f);
    float v=0.f;
    for(int i=0;i<32;i++){ float d=z[i]-m; v+=d*d; }
    v *= (1.f/32.f);
    float rs=rsqrtf(v+1e-5f);
    for(int i=0;i<32;i++) z[i]=fmaxf((z[i]-m)*rs*clng[i]+clnb[i],0.f);
  }
  __syncthreads();
  if(tid<2){
    float s=c2b[tid];
    #pragma unroll
    for(int k=0;k<32;k++) s += z[k]*c2w[k*2+tid];
    out[b*2+tid]=s;
  }
}

extern "C" void kernel_launch(void* const* d_in, const int* in_sizes, int n_in,
                              void* d_out, int out_size, void* d_ws, size_t ws_size,
                              hipStream_t stream) {
  const float* x0 = (const float*)d_in[0];
  const float* x1 = (const float*)d_in[1];
  const float* x2 = (const float*)d_in[2];
  const float* x3 = (const float*)d_in[3];
  const float* x4 = (const float*)d_in[4];
  const float* x5 = (const float*)d_in[5];
  const float* gfeat   = (const float*)d_in[6];
  const float* alpha_p = (const float*)d_in[7];
  const float* g1w = (const float*)d_in[8];
  const float* g1b = (const float*)d_in[9];
  const float* g2w = (const float*)d_in[10];
  const float* g2b = (const float*)d_in[11];
  const float* rlg = (const float*)d_in[12];
  const float* rlb = (const float*)d_in[13];
  const float* spqkvw = (const float*)d_in[14];
  const float* spqkvb = (const float*)d_in[15];
  const float* spow = (const float*)d_in[16];
  const float* spob = (const float*)d_in[17];
  const float* spl1g = (const float*)d_in[18];
  const float* spl1b = (const float*)d_in[19];
  const float* spf1w = (const float*)d_in[20];
  const float* spf1b = (const float*)d_in[21];
  const float* spf2w = (const float*)d_in[22];
  const float* spf2b = (const float*)d_in[23];
  const float* spl2g = (const float*)d_in[24];
  const float* spl2b = (const float*)d_in[25];
  const float* rlogit = (const float*)d_in[26];
  const float* gate1w = (const float*)d_in[27];
  const float* gate1b = (const float*)d_in[28];
  const float* gate2w = (const float*)d_in[29];
  const float* gate2b = (const float*)d_in[30];
  const float* caqkvw = (const float*)d_in[31];
  const float* caqkvb = (const float*)d_in[32];
  const float* caow = (const float*)d_in[33];
  const float* caob = (const float*)d_in[34];
  const float* calng = (const float*)d_in[35];
  const float* calnb = (const float*)d_in[36];
  const float* globw = (const float*)d_in[37];
  const float* globb = (const float*)d_in[38];
  const float* glng = (const float*)d_in[39];
  const float* glnb = (const float*)d_in[40];
  const float* flng = (const float*)d_in[41];
  const float* flnb = (const float*)d_in[42];
  const float* tpqkvw = (const float*)d_in[43];
  const float* tpqkvb = (const float*)d_in[44];
  const float* tpow = (const float*)d_in[45];
  const float* tpob = (const float*)d_in[46];
  const float* tpl1g = (const float*)d_in[47];
  const float* tpl1b = (const float*)d_in[48];
  const float* tpf1w = (const float*)d_in[49];
  const float* tpf1b = (const float*)d_in[50];
  const float* tpf2w = (const float*)d_in[51];
  const float* tpf2b = (const float*)d_in[52];
  const float* tpl2g = (const float*)d_in[53];
  const float* tpl2b = (const float*)d_in[54];
  const float* apw = (const float*)d_in[55];
  const float* apb = (const float*)d_in[56];
  const float* c1w = (const float*)d_in[57];
  const float* c1b = (const float*)d_in[58];
  const float* clng = (const float*)d_in[59];
  const float* clnb = (const float*)d_in[60];
  const float* c2w = (const float*)d_in[61];
  const float* c2b = (const float*)d_in[62];

  float* ws = (float*)d_ws;
  float* tok   = ws;                               // 4096*384
  float* fused = tok   + (size_t)NFRM*384;         // 4096*128
  float* qkv   = fused + (size_t)NFRM*128;         // 4096*384
  float* obuf  = qkv   + (size_t)NFRM*384;         // 4096*128
  float* part  = obuf  + (size_t)NFRM*128;         // partials: 3,145,728 floats
  size_t part_elems = (size_t)2*24576*64;
  unsigned short* pk = (unsigned short*)(part + part_elems);
  unsigned short* sp1h = pk;
  unsigned short* sp1l = sp1h + 131072;
  unsigned short* sp2h = sp1l + 131072;
  unsigned short* sp2l = sp2h + 131072;
  unsigned short* tp1h = sp2l + 131072;
  unsigned short* tp1l = tp1h + 262144;
  unsigned short* tp2h = tp1l + 262144;
  unsigned short* tp2l = tp2h + 262144;
  size_t pack_ushorts = 4*131072 + 4*262144;
  size_t need = ((size_t)NFRM*384 + NFRM*128 + NFRM*384 + NFRM*128 + part_elems)*4
              + pack_ushorts*2;
  bool mfma_ok = (ws_size >= need);

  float* attnPO = (float*)(pk + pack_ushorts);
  float* attnPM = attnPO + (size_t)8*64*256*32;
  float* attnPL = attnPM + (size_t)8*64*256;
  size_t need2 = need + ((size_t)8*64*256*32 + 2*(size_t)8*64*256)*4;
  bool attn_ok = (ws_size >= need2);

  if(mfma_ok){
    pack_all_kernel<<<1536,64,0,stream>>>(spf1w,spf2w,tpf1w,tpf2w,
                                          sp1h,sp1l,sp2h,sp2l,tp1h,tp1l,tp2h,tp2l);
  }

  // gcn: 2 waves/block, F=4 frames/wave -> grid (NFRM/8, 6)
  gcn_kernel<<<dim3(NFRM/8,6),128,0,stream>>>(x0,x1,x2,x3,x4,x5,g1w,g1b,g2w,g2b,rlg,rlb,tok);
  sp_attn_kernel<<<NFRM/4,256,0,stream>>>(tok,spqkvw,spqkvb,spow,spob,spl1g,spl1b);
  if(mfma_ok){
    ffn_mfma_partial<64,2><<<dim3(768,2),256,0,stream>>>(tok,part,sp1h,sp1l,spf1b,sp2h,sp2l);
    fuse_kernel<<<NFRM/4,256,0,stream>>>(tok,part,1,spf2b,spl2g,spl2b,
                                      gfeat,alpha_p,rlogit,gate1w,gate1b,gate2w,gate2b,
                                      caqkvw,caqkvb,caow,caob,calng,calnb,
                                      globw,globb,glng,glnb,flng,flnb,fused);
  } else {
    ffn_ln_kernel<64,32><<<768,256,0,stream>>>(tok,tok,spf1w,spf1b,spf2w,spf2b,spl2g,spl2b);
    fuse_kernel<<<NFRM/4,256,0,stream>>>(tok,part,0,spf2b,spl2g,spl2b,
                                      gfeat,alpha_p,rlogit,gate1w,gate1b,gate2w,gate2b,
                                      caqkvw,caqkvb,caow,caob,calng,calnb,
                                      globw,globb,glng,glnb,flng,flnb,fused);
  }
  tqkv_gemm_kernel<<<dim3(128,3),256,0,stream>>>(fused,qkv,tpqkvw,tpqkvb);
  if(attn_ok){
    tattn_split_kernel<<<dim3(NBATCH,4,8),256,0,stream>>>(qkv,attnPO,attnPM,attnPL);
    attn_combine_kernel<<<64*32,256,0,stream>>>(attnPO,attnPM,attnPL,obuf);
  } else {
    tattn_kernel<<<dim3(NBATCH,4),256,0,stream>>>(qkv,obuf);
  }
  tproj_gemm_kernel<<<128,256,0,stream>>>(obuf,fused,tpow,tpob,tpl1g,tpl1b);
  if(mfma_ok){
    ffn_mfma_partial<128,4><<<dim3(128,4),256,0,stream>>>(fused,part,tp1h,tp1l,tpf1b,tp2h,tp2l);
    ffn_combine_kernel<128,4><<<NFRM/4,256,0,stream>>>(fused,part,obuf,tpf2b,tpl2g,tpl2b);
  } else {
    ffn_ln_kernel<128,16><<<256,256,0,stream>>>(fused,obuf,tpf1w,tpf1b,tpf2w,tpf2b,tpl2g,tpl2b);
  }
  pool_cls_kernel<<<NBATCH,256,0,stream>>>(obuf,apw,apb,c1w,c1b,clng,clnb,c2w,c2b,(float*)d_out);
}

// Round 15
// 326.341 us; speedup vs baseline: 1.1569x; 1.0449x over previous
//
#include <hip/hip_runtime.h>
#include <math.h>
#include <stddef.h>

#define NFRM 4096   // B*T
#define NBATCH 16

typedef __attribute__((ext_vector_type(8))) short short8v;
typedef __attribute__((ext_vector_type(4))) float f32x4;
#define MFMA_BF16(a,b,c) __builtin_amdgcn_mfma_f32_16x16x32_bf16(a,b,c,0,0,0)

__device__ inline float wsum64(float v){
  #pragma unroll
  for(int m=32;m>=1;m>>=1) v += __shfl_xor(v, m, 64);
  return v;
}

__device__ inline float pe_val(int t,int d){
  int k = d >> 1;
  float div = expf(-(float)(2*k) * (9.210340371976184f/128.f));
  float ang = (float)t * div;
  return (d & 1) ? cosf(ang) : sinf(ang);
}

// split x into hi+lo bf16 (round-to-nearest-even)
__device__ inline void bf16split(float x, unsigned short &h, unsigned short &l){
  unsigned u = __float_as_uint(x);
  unsigned r = (u + 0x7FFFu + ((u>>16)&1u)) & 0xFFFF0000u;
  h = (unsigned short)(r>>16);
  float rem = x - __uint_as_float(r);
  unsigned u2 = __float_as_uint(rem);
  unsigned r2 = (u2 + 0x7FFFu + ((u2>>16)&1u));
  l = (unsigned short)(r2>>16);
}

// ---------------- fused pack: all 4 FFN weights into MFMA B-fragment layout (hi/lo bf16)
__global__ __launch_bounds__(64) void pack_all_kernel(
    const float* __restrict__ spf1w, const float* __restrict__ spf2w,
    const float* __restrict__ tpf1w, const float* __restrict__ tpf2w,
    unsigned short* __restrict__ sp1h, unsigned short* __restrict__ sp1l,
    unsigned short* __restrict__ sp2h, unsigned short* __restrict__ sp2l,
    unsigned short* __restrict__ tp1h, unsigned short* __restrict__ tp1l,
    unsigned short* __restrict__ tp2h, unsigned short* __restrict__ tp2l)
{
  int b = blockIdx.x, lane = threadIdx.x;
  const float* w; unsigned short *hi, *lo; int K, N, ntile, s;
  if(b < 256){        w=spf1w; hi=sp1h; lo=sp1l; K=64;   N=2048; ntile=b&127;        s=b>>7; }
  else if(b < 512){   int bb=b-256;  w=spf2w; hi=sp2h; lo=sp2l; K=2048; N=64;   ntile=bb&3;   s=bb>>2; }
  else if(b < 1024){  int bb=b-512;  w=tpf1w; hi=tp1h; lo=tp1l; K=128;  N=2048; ntile=bb&127; s=bb>>7; }
  else {              int bb=b-1024; w=tpf2w; hi=tp2h; lo=tp2l; K=2048; N=128;  ntile=bb&7;   s=bb>>3; }
  int n = ntile*16 + (lane & 15);
  int k0 = s*32 + (lane>>4)*8;
  size_t off = (((size_t)ntile*(K/32) + s)*64 + lane)*8;
  #pragma unroll
  for(int e=0;e<8;e++){
    float v = w[(size_t)(k0+e)*N + n];
    unsigned short h,l;
    bf16split(v,h,l);
    hi[off+e]=h; lo[off+e]=l;
  }
}

// ---------------- MFMA FFN partial: P[s] = relu(X@W1+b1)[:,slice] @ W2[slice,:]
template<int D, int NS>
__global__ __launch_bounds__(256) void ffn_mfma_partial(
    const float* __restrict__ X, float* __restrict__ P,
    const unsigned short* __restrict__ w1h, const unsigned short* __restrict__ w1l,
    const float* __restrict__ b1,
    const unsigned short* __restrict__ w2h, const unsigned short* __restrict__ w2l)
{
  constexpr int TM=32, JC=128;
  constexpr int KS1 = D/32;
  constexpr int NT2W = (D/16)/4;
  constexpr int HS = 2048/NS;
  constexpr int NCH = HS/JC;
  constexpr int HP = JC + 8;
  __shared__ unsigned short Hh[TM][HP];
  __shared__ unsigned short Hl[TM][HP];
  int tid = threadIdx.x;
  int lane = tid & 63, w = tid >> 6;
  int ar = lane & 15, ak = lane >> 4;
  size_t Ntok = (size_t)gridDim.x*TM;
  const float* Xb = X + (size_t)blockIdx.x*TM*D;

  short8v xah[2][KS1], xal[2][KS1];
  #pragma unroll
  for(int mt=0;mt<2;mt++){
    #pragma unroll
    for(int s=0;s<KS1;s++){
      const float* xp = Xb + (size_t)(mt*16+ar)*D + s*32 + ak*8;
      #pragma unroll
      for(int e=0;e<8;e++){
        unsigned short h,l;
        bf16split(xp[e],h,l);
        xah[mt][s][e]=(short)h; xal[mt][s][e]=(short)l;
      }
    }
  }

  f32x4 acc2[2][NT2W];
  #pragma unroll
  for(int mt=0;mt<2;mt++)
    #pragma unroll
    for(int nt=0;nt<NT2W;nt++)
      acc2[mt][nt] = (f32x4){0.f,0.f,0.f,0.f};

  for(int ch=0; ch<NCH; ch++){
    int jc = blockIdx.y*HS + ch*JC;
    f32x4 a1[2][2];
    #pragma unroll
    for(int mt=0;mt<2;mt++){ a1[mt][0]=(f32x4){0,0,0,0}; a1[mt][1]=(f32x4){0,0,0,0}; }
    #pragma unroll
    for(int s=0;s<KS1;s++){
      #pragma unroll
      for(int nt=0;nt<2;nt++){
        int ntile1 = (jc + w*32 + nt*16) >> 4;
        size_t off = (((size_t)ntile1*KS1 + s)*64 + lane)*8;
        short8v bh = *(const short8v*)(w1h + off);
        short8v bl = *(const short8v*)(w1l + off);
        #pragma unroll
        for(int mt=0;mt<2;mt++){
          a1[mt][nt] = MFMA_BF16(xah[mt][s], bh, a1[mt][nt]);
          a1[mt][nt] = MFMA_BF16(xah[mt][s], bl, a1[mt][nt]);
          a1[mt][nt] = MFMA_BF16(xal[mt][s], bh, a1[mt][nt]);
        }
      }
    }
    __syncthreads();
    #pragma unroll
    for(int nt=0;nt<2;nt++){
      int colBase = w*32 + nt*16 + ar;
      float bval = b1[jc + colBase];
      #pragma unroll
      for(int mt=0;mt<2;mt++){
        #pragma unroll
        for(int r=0;r<4;r++){
          float hv = a1[mt][nt][r] + bval;
          hv = fmaxf(hv, 0.f);
          unsigned short h,l;
          bf16split(hv,h,l);
          int row = mt*16 + ak*4 + r;
          Hh[row][colBase]=h; Hl[row][colBase]=l;
        }
      }
    }
    __syncthreads();
    #pragma unroll
    for(int s2=0;s2<4;s2++){
      short8v ah[2], al[2];
      #pragma unroll
      for(int mt=0;mt<2;mt++){
        ah[mt] = *(const short8v*)&Hh[mt*16+ar][s2*32 + ak*8];
        al[mt] = *(const short8v*)&Hl[mt*16+ar][s2*32 + ak*8];
      }
      #pragma unroll
      for(int nt=0;nt<NT2W;nt++){
        int ntile2 = w*NT2W + nt;
        int kstep2 = (jc >> 5) + s2;
        size_t off = (((size_t)ntile2*64 + kstep2)*64 + lane)*8;
        short8v bh = *(const short8v*)(w2h + off);
        short8v bl = *(const short8v*)(w2l + off);
        #pragma unroll
        for(int mt=0;mt<2;mt++){
          acc2[mt][nt] = MFMA_BF16(ah[mt], bh, acc2[mt][nt]);
          acc2[mt][nt] = MFMA_BF16(ah[mt], bl, acc2[mt][nt]);
          acc2[mt][nt] = MFMA_BF16(al[mt], bh, acc2[mt][nt]);
        }
      }
    }
  }
  float* Pb = P + (size_t)blockIdx.y*Ntok*D + (size_t)blockIdx.x*TM*D;
  #pragma unroll
  for(int mt=0;mt<2;mt++){
    #pragma unroll
    for(int nt=0;nt<NT2W;nt++){
      int col = (w*NT2W + nt)*16 + ar;
      #pragma unroll
      for(int r=0;r<4;r++){
        int row = mt*16 + ak*4 + r;
        Pb[(size_t)row*D + col] = acc2[mt][nt][r];
      }
    }
  }
}

// ---------------- combine partials: Y = LN(X + sum_s P_s + b2)  (temporal path)
template<int D, int NS>
__global__ __launch_bounds__(256) void ffn_combine_kernel(
    const float* __restrict__ X, const float* __restrict__ P,
    float* __restrict__ Y,
    const float* __restrict__ b2,
    const float* __restrict__ lg, const float* __restrict__ lb)
{
  constexpr int EPL = D/64;
  int tid=threadIdx.x;
  int lane = tid & 63;
  size_t Ntok = (size_t)gridDim.x*4;
  size_t row = (size_t)blockIdx.x*4 + (tid>>6);
  size_t base = row*D;
  float e[EPL];
  float s=0.f;
  #pragma unroll
  for(int i=0;i<EPL;i++){
    int c = i*64+lane;
    float v = X[base+c] + b2[c];
    #pragma unroll
    for(int sp=0;sp<NS;sp++) v += P[(size_t)sp*Ntok*D + base + c];
    e[i]=v; s+=v;
  }
  float mm = wsum64(s)*(1.f/D);
  float s2=0.f;
  #pragma unroll
  for(int i=0;i<EPL;i++){ float d=e[i]-mm; s2+=d*d; }
  float rs = rsqrtf(wsum64(s2)*(1.f/D)+1e-5f);
  #pragma unroll
  for(int i=0;i<EPL;i++){
    int c=i*64+lane;
    Y[base+c] = (e[i]-mm)*rs*lg[c]+lb[c];
  }
}

// ---------------- Kernel 1: GCN — 2 frames/block, wave-synchronous (round-12 proven version)
__global__ __launch_bounds__(128) void gcn_kernel(
    const float* __restrict__ x0,const float* __restrict__ x1,
    const float* __restrict__ x2,const float* __restrict__ x3,
    const float* __restrict__ x4,const float* __restrict__ x5,
    const float* __restrict__ g1w,const float* __restrict__ g1b,
    const float* __restrict__ g2w,const float* __restrict__ g2b,
    const float* __restrict__ rg,const float* __restrict__ rb,
    float* __restrict__ tok)
{
  int tid=threadIdx.x;
  int lane = tid & 63, w = tid >> 6;
  int f = blockIdx.x*2 + w;
  int r = blockIdx.y;
  int n = (r==5) ? 20 : ((r==2 || r==3) ? 11 : 9);
  const float* xr = (r==0)?x0:(r==1)?x1:(r==2)?x2:(r==3)?x3:(r==4)?x4:x5;
  int c = lane & 31;

  __shared__ float xs[2][20*12];      // stride-12 padded (f4-aligned)
  __shared__ float t0g[2][24*32];     // rows 0,1 and n+2,n+3 are zero guards
  __shared__ float t1s[2][20*32];
  __shared__ float Cw[2][20][5];      // per-wave adjacency coefs

  float W1c[11], W2c[32];
  #pragma unroll
  for(int k=0;k<11;k++) W1c[k]=g1w[r*352 + k*32 + c];
  #pragma unroll
  for(int k=0;k<32;k++) W2c[k]=g2w[r*1024 + k*32 + c];
  float b1c = g1b[r*32+c], b2c = g2b[r*32+c];

  for(int i=lane;i<100;i+=64){
    int node=i/5, j=i%5, m=node+j-2;
    float cf=0.f;
    if(node<n && m>=0 && m<n){
      int di = 1 + min(node,2) + min(n-1-node,2);
      int dm = 1 + min(m,2) + min(n-1-m,2);
      cf = rsqrtf((float)(di*dm));
    }
    Cw[w][node][j]=cf;
  }
  for(int i=lane;i<128;i+=64){
    int row4=i>>5, col=i&31;
    int row = (row4<2) ? row4 : (n+row4);
    t0g[w][row*32+col]=0.f;
  }
  for(int i=lane;i<n*12;i+=64){
    int node=i/12, k=i-node*12;
    xs[w][i] = (k<11) ? xr[(size_t)f*n*11 + node*11 + k] : 0.f;
  }
  __builtin_amdgcn_wave_barrier();
  for(int i=lane;i<n*32;i+=64){
    int node=i>>5;
    float4 xa = *(const float4*)&xs[w][node*12];
    float4 xb = *(const float4*)&xs[w][node*12+4];
    float4 xc = *(const float4*)&xs[w][node*12+8];
    float s = xa.x*W1c[0]+xa.y*W1c[1]+xa.z*W1c[2]+xa.w*W1c[3]
            + xb.x*W1c[4]+xb.y*W1c[5]+xb.z*W1c[6]+xb.w*W1c[7]
            + xc.x*W1c[8]+xc.y*W1c[9]+xc.z*W1c[10];
    t0g[w][(node+2)*32+c]=s;
  }
  __builtin_amdgcn_wave_barrier();
  for(int i=lane;i<n*32;i+=64){
    int node=i>>5;
    float s=b1c;
    #pragma unroll
    for(int j=0;j<5;j++) s += Cw[w][node][j]*t0g[w][(node+j)*32+c];
    t1s[w][i]=fmaxf(s,0.f);
  }
  __builtin_amdgcn_wave_barrier();
  for(int i=lane;i<n*32;i+=64){
    int node=i>>5;
    float s=0.f;
    #pragma unroll
    for(int k0=0;k0<32;k0+=4){
      float4 tv = *(const float4*)&t1s[w][node*32+k0];
      s += tv.x*W2c[k0] + tv.y*W2c[k0+1] + tv.z*W2c[k0+2] + tv.w*W2c[k0+3];
    }
    t0g[w][(node+2)*32+c]=s;
  }
  __builtin_amdgcn_wave_barrier();
  for(int i=lane;i<n*32;i+=64){
    int node=i>>5;
    float s=b2c;
    #pragma unroll
    for(int j=0;j<5;j++) s += Cw[w][node][j]*t0g[w][(node+j)*32+c];
    t1s[w][i]=fmaxf(s,0.f);
  }
  __builtin_amdgcn_wave_barrier();
  float v;
  if(lane<32){
    float s=0.f;
    for(int m=0;m<n;m++) s += t1s[w][m*32+lane];
    v = s/(float)n;
  } else {
    float mx=-1e30f;
    for(int m=0;m<n;m++) mx = fmaxf(mx, t1s[w][m*32+c]);
    v = mx;
  }
  float m1 = wsum64(v)*(1.f/64.f);
  float d1 = v - m1;
  float var = wsum64(d1*d1)*(1.f/64.f);
  float y = d1*rsqrtf(var+1e-5f)*rg[r*64+lane] + rb[r*64+lane];
  tok[((size_t)f*6+r)*64+lane] = y;
}

// ---------------- Kernel 2a: spatial attention + residual + LN1 — 4 frames/block, block-wide GEMMs
__global__ __launch_bounds__(256) void sp_attn_kernel(
    float* __restrict__ tok,
    const float* __restrict__ qkvw,const float* __restrict__ qkvb,
    const float* __restrict__ ow,const float* __restrict__ ob,
    const float* __restrict__ l1g,const float* __restrict__ l1b)
{
  __shared__ float Xs[24][64];
  __shared__ float QKV[24][192];
  __shared__ float SC[4][144];
  __shared__ float AO[24][64];
  int tid=threadIdx.x;
  int f0 = blockIdx.x*4;
  float* Xf = &Xs[0][0];
  for(int i=tid;i<1536;i+=256) Xf[i] = tok[(size_t)f0*384 + i];
  __syncthreads();
  {
    int cg = tid & 31, c0 = cg*6;
    int rg = tid >> 5, r0 = rg*3;
    float acc[3][6];
    #pragma unroll
    for(int m=0;m<3;m++)
      #pragma unroll
      for(int j=0;j<6;j++) acc[m][j]=qkvb[c0+j];
    for(int k=0;k<64;k++){
      float wv[6];
      #pragma unroll
      for(int j=0;j<6;j++) wv[j]=qkvw[k*192+c0+j];
      float xv0=Xs[r0][k], xv1=Xs[r0+1][k], xv2=Xs[r0+2][k];
      #pragma unroll
      for(int j=0;j<6;j++){
        acc[0][j]+=xv0*wv[j];
        acc[1][j]+=xv1*wv[j];
        acc[2][j]+=xv2*wv[j];
      }
    }
    #pragma unroll
    for(int m=0;m<3;m++)
      #pragma unroll
      for(int j=0;j<6;j++) QKV[r0+m][c0+j]=acc[m][j];
  }
  __syncthreads();
  for(int i=tid;i<576;i+=256){
    int fr=i/144, rest=i%144;
    int h=rest/36, qi=(rest%36)/6, ki=rest%6;
    float s=0.f;
    #pragma unroll
    for(int d=0;d<16;d++) s += QKV[fr*6+qi][h*16+d]*QKV[fr*6+ki][64+h*16+d];
    SC[fr][rest]=s*0.25f;
  }
  __syncthreads();
  if(tid<96){
    int fr=tid/24, idx=tid%24;
    int base=idx*6;
    float mx=-1e30f;
    for(int k=0;k<6;k++) mx=fmaxf(mx,SC[fr][base+k]);
    float sm=0.f;
    for(int k=0;k<6;k++){ float e=expf(SC[fr][base+k]-mx); SC[fr][base+k]=e; sm+=e; }
    float rr=1.f/sm;
    for(int k=0;k<6;k++) SC[fr][base+k]*=rr;
  }
  __syncthreads();
  for(int i=tid;i<1536;i+=256){
    int fr=i/384, rem=i%384;
    int row=rem/64, c=rem&63, h=c/16;
    float s=0.f;
    #pragma unroll
    for(int k=0;k<6;k++) s += SC[fr][h*36+row*6+k]*QKV[fr*6+k][128+c];
    AO[fr*6+row][c]=s;
  }
  __syncthreads();
  {
    int cg = tid & 31, c0 = cg*2;
    int rg = tid >> 5, r0 = rg*3;
    float acc[3][2];
    #pragma unroll
    for(int m=0;m<3;m++){ acc[m][0]=ob[c0]; acc[m][1]=ob[c0+1]; }
    for(int k=0;k<64;k++){
      float w0=ow[k*64+c0], w1=ow[k*64+c0+1];
      float a0=AO[r0][k], a1=AO[r0+1][k], a2=AO[r0+2][k];
      acc[0][0]+=a0*w0; acc[0][1]+=a0*w1;
      acc[1][0]+=a1*w0; acc[1][1]+=a1*w1;
      acc[2][0]+=a2*w0; acc[2][1]+=a2*w1;
    }
    #pragma unroll
    for(int m=0;m<3;m++){
      QKV[r0+m][c0]   = Xs[r0+m][c0]   + acc[m][0];
      QKV[r0+m][c0+1] = Xs[r0+m][c0+1] + acc[m][1];
    }
  }
  __syncthreads();
  {
    int lane = tid & 63, w = tid >> 6;
    #pragma unroll
    for(int rr=0;rr<6;rr++){
      int row = w*6+rr;
      float v=QKV[row][lane];
      float mm=wsum64(v)*(1.f/64.f);
      float d=v-mm;
      float var=wsum64(d*d)*(1.f/64.f);
      tok[(size_t)f0*384 + row*64 + lane]=d*rsqrtf(var+1e-5f)*l1g[lane]+l1b[lane];
    }
  }
}

// ---------------- fused fp32 FFN + residual + LN (fallback path)
template<int D, int TM>
__global__ __launch_bounds__(256) void ffn_ln_kernel(
    const float* __restrict__ X, float* __restrict__ Yout,
    const float* __restrict__ w1,const float* __restrict__ b1,
    const float* __restrict__ w2,const float* __restrict__ b2,
    const float* __restrict__ lg,const float* __restrict__ lb)
{
  constexpr int JC = 128;
  constexpr int JS = JC + 4;
  constexpr int M1 = TM/8;
  constexpr int CG = D/4;
  constexpr int MG2 = 256/CG;
  constexpr int M2 = TM/MG2;
  __shared__ float Xs[TM*D];
  __shared__ float Hs[TM*JS];
  int tid=threadIdx.x;
  const float* Xb = X + (size_t)blockIdx.x*TM*D;
  for(int i=tid;i<TM*D;i+=256) Xs[i]=Xb[i];

  int jg = tid & 31, j0 = jg*4;
  int mg1 = tid >> 5;
  int m10 = mg1*M1;
  int cg = tid % CG, c0 = cg*4;
  int mg2 = tid / CG;
  int m20 = mg2*M2;

  float acc[M2][4];
  #pragma unroll
  for(int m=0;m<M2;m++){ acc[m][0]=0.f;acc[m][1]=0.f;acc[m][2]=0.f;acc[m][3]=0.f; }

  __syncthreads();
  for(int jc=0;jc<2048;jc+=JC){
    float a1[M1][4];
    float4 bv = *(const float4*)&b1[jc+j0];
    #pragma unroll
    for(int m=0;m<M1;m++){ a1[m][0]=bv.x;a1[m][1]=bv.y;a1[m][2]=bv.z;a1[m][3]=bv.w; }
    for(int k0=0;k0<D;k0+=4){
      float4 wr0 = *(const float4*)&w1[(size_t)(k0+0)*2048 + jc + j0];
      float4 wr1 = *(const float4*)&w1[(size_t)(k0+1)*2048 + jc + j0];
      float4 wr2 = *(const float4*)&w1[(size_t)(k0+2)*2048 + jc + j0];
      float4 wr3 = *(const float4*)&w1[(size_t)(k0+3)*2048 + jc + j0];
      #pragma unroll
      for(int m=0;m<M1;m++){
        float4 xv = *(const float4*)&Xs[(m10+m)*D + k0];
        a1[m][0] += xv.x*wr0.x + xv.y*wr1.x + xv.z*wr2.x + xv.w*wr3.x;
        a1[m][1] += xv.x*wr0.y + xv.y*wr1.y + xv.z*wr2.y + xv.w*wr3.y;
        a1[m][2] += xv.x*wr0.z + xv.y*wr1.z + xv.z*wr2.z + xv.w*wr3.z;
        a1[m][3] += xv.x*wr0.w + xv.y*wr1.w + xv.z*wr2.w + xv.w*wr3.w;
      }
    }
    #pragma unroll
    for(int m=0;m<M1;m++){
      float4 hv;
      hv.x=fmaxf(a1[m][0],0.f); hv.y=fmaxf(a1[m][1],0.f);
      hv.z=fmaxf(a1[m][2],0.f); hv.w=fmaxf(a1[m][3],0.f);
      *(float4*)&Hs[(m10+m)*JS + j0] = hv;
    }
    __syncthreads();
    for(int jj0=0;jj0<JC;jj0+=4){
      float4 w20 = *(const float4*)&w2[(size_t)(jc+jj0+0)*D + c0];
      float4 w21 = *(const float4*)&w2[(size_t)(jc+jj0+1)*D + c0];
      float4 w22 = *(const float4*)&w2[(size_t)(jc+jj0+2)*D + c0];
      float4 w23 = *(const float4*)&w2[(size_t)(jc+jj0+3)*D + c0];
      #pragma unroll
      for(int m=0;m<M2;m++){
        float4 hv = *(const float4*)&Hs[(m20+m)*JS + jj0];
        acc[m][0] += hv.x*w20.x + hv.y*w21.x + hv.z*w22.x + hv.w*w23.x;
        acc[m][1] += hv.x*w20.y + hv.y*w21.y + hv.z*w22.y + hv.w*w23.y;
        acc[m][2] += hv.x*w20.z + hv.y*w21.z + hv.z*w22.z + hv.w*w23.z;
        acc[m][3] += hv.x*w20.w + hv.y*w21.w + hv.z*w22.w + hv.w*w23.w;
      }
    }
    __syncthreads();
  }
  {
    float4 b2v = *(const float4*)&b2[c0];
    #pragma unroll
    for(int m=0;m<M2;m++){
      int row = m20+m;
      float4 xv = *(const float4*)&Xs[row*D + c0];
      float4 yv;
      yv.x = xv.x + acc[m][0] + b2v.x;
      yv.y = xv.y + acc[m][1] + b2v.y;
      yv.z = xv.z + acc[m][2] + b2v.z;
      yv.w = xv.w + acc[m][3] + b2v.w;
      *(float4*)&Hs[row*D + c0] = yv;
    }
  }
  __syncthreads();
  constexpr int EPL = D/64;
  int lane = tid & 63, wv = tid >> 6;
  float* Yb = Yout + (size_t)blockIdx.x*TM*D;
  for(int row=wv; row<TM; row+=4){
    float e[EPL];
    float s=0.f;
    #pragma unroll
    for(int i=0;i<EPL;i++){ e[i]=Hs[row*D + i*64 + lane]; s+=e[i]; }
    float mm = wsum64(s)*(1.f/D);
    float s2=0.f;
    #pragma unroll
    for(int i=0;i<EPL;i++){ float d=e[i]-mm; s2+=d*d; }
    float rs = rsqrtf(wsum64(s2)*(1.f/D)+1e-5f);
    #pragma unroll
    for(int i=0;i<EPL;i++)
      Yb[row*D + i*64 + lane] = (e[i]-mm)*rs*lg[i*64+lane]+lb[i*64+lane];
  }
}

// ---------------- Kernel 3: fuse — 4 frames/block; inlines spatial FFN combine (partials+b2+LN2)
__global__ __launch_bounds__(256) void fuse_kernel(
    const float* __restrict__ tok, const float* __restrict__ part, int do_combine,
    const float* __restrict__ sb2, const float* __restrict__ sl2g, const float* __restrict__ sl2b,
    const float* __restrict__ gfeat,
    const float* __restrict__ alpha_p, const float* __restrict__ rlogit,
    const float* __restrict__ g1w,const float* __restrict__ g1b,
    const float* __restrict__ g2w,const float* __restrict__ g2b,
    const float* __restrict__ caqw,const float* __restrict__ caqb,
    const float* __restrict__ caow,const float* __restrict__ caob,
    const float* __restrict__ calng,const float* __restrict__ calnb,
    const float* __restrict__ gw,const float* __restrict__ gb,
    const float* __restrict__ glng,const float* __restrict__ glnb,
    const float* __restrict__ flng,const float* __restrict__ flnb,
    float* __restrict__ fused)
{
  int tid=threadIdx.x;
  int lane = tid & 63, w = tid >> 6;
  int f = blockIdx.x*4 + w;
  __shared__ float X[4][384];
  __shared__ float G1[4][192];
  __shared__ float gt[4][6];
  __shared__ float qv[4][64];
  __shared__ float Qs[4][64];
  __shared__ float KK[4][384], VV[4][384];
  __shared__ float sc[4][24];
  __shared__ float AOs[4][64];

  const float* trow = tok + (size_t)f*384;
  if(do_combine){
    #pragma unroll
    for(int row=0;row<6;row++){
      size_t grow = (size_t)f*6 + row;
      float v = trow[row*64+lane] + sb2[lane]
              + part[grow*64 + lane]
              + part[(size_t)24576*64 + grow*64 + lane];
      float mm = wsum64(v)*(1.f/64.f);
      float d = v-mm;
      float var = wsum64(d*d)*(1.f/64.f);
      X[w][row*64+lane] = d*rsqrtf(var+1e-5f)*sl2g[lane]+sl2b[lane];
    }
  } else {
    for(int i=lane;i<384;i+=64) X[w][i]=trow[i];
  }
  __syncthreads();
  for(int i=lane;i<192;i+=64){
    int rr=i/32, j=i%32;
    float s=g1b[j];
    #pragma unroll
    for(int k=0;k<64;k++) s += X[w][rr*64+k]*g1w[k*32+j];
    G1[w][i]=fmaxf(s,0.f);
  }
  __syncthreads();
  if(lane<6){
    float s=g2b[0];
    #pragma unroll
    for(int k=0;k<32;k++) s += G1[w][lane*32+k]*g2w[k];
    float gate = 1.f/(1.f+expf(-s));
    float rw = log1pf(expf(rlogit[lane]));
    gt[w][lane]=gate*rw;
  }
  __syncthreads();
  for(int i=lane;i<384;i+=64) X[w][i]*=gt[w][i/64];
  __syncthreads();
  {
    float s=0.f;
    #pragma unroll
    for(int rr=0;rr<6;rr++) s+=X[w][rr*64+lane];
    qv[w][lane]=s*(1.f/6.f);
  }
  __syncthreads();
  {
    float s=caqb[lane];
    #pragma unroll
    for(int k=0;k<64;k++) s += qv[w][k]*caqw[k*192+lane];
    Qs[w][lane]=s;
  }
  for(int i=lane;i<384;i+=64){
    int rr=i/64, c=i%64;
    float sk=caqb[64+c], sv=caqb[128+c];
    #pragma unroll
    for(int k=0;k<64;k++){
      float xv=X[w][rr*64+k];
      sk += xv*caqw[k*192+64+c];
      sv += xv*caqw[k*192+128+c];
    }
    KK[w][i]=sk; VV[w][i]=sv;
  }
  __syncthreads();
  if(lane<24){
    int h=lane/6, ki=lane%6;
    float s=0.f;
    #pragma unroll
    for(int d=0;d<16;d++) s += Qs[w][h*16+d]*KK[w][ki*64+h*16+d];
    sc[w][lane]=s*0.25f;
  }
  __syncthreads();
  if(lane<4){
    float mx=-1e30f;
    for(int k=0;k<6;k++) mx=fmaxf(mx,sc[w][lane*6+k]);
    float sm=0.f;
    for(int k=0;k<6;k++){ float e=expf(sc[w][lane*6+k]-mx); sc[w][lane*6+k]=e; sm+=e; }
    float rr=1.f/sm;
    for(int k=0;k<6;k++) sc[w][lane*6+k]*=rr;
  }
  __syncthreads();
  {
    int h=lane/16;
    float s=0.f;
    #pragma unroll
    for(int k=0;k<6;k++) s += sc[w][h*6+k]*VV[w][k*64+lane];
    AOs[w][lane]=s;
  }
  __syncthreads();
  float pr;
  {
    float s=caob[lane];
    #pragma unroll
    for(int k=0;k<64;k++) s += AOs[w][k]*caow[k*64+lane];
    pr = qv[w][lane] + s;
  }
  float m1=wsum64(pr)*(1.f/64.f);
  float d1=pr-m1;
  float v1=wsum64(d1*d1)*(1.f/64.f);
  float fr = d1*rsqrtf(v1+1e-5f)*calng[lane]+calnb[lane];
  float gvv;
  {
    float s=gb[lane];
    #pragma unroll
    for(int k=0;k<4;k++) s += gfeat[(size_t)f*4+k]*gw[k*64+lane];
    gvv=s;
  }
  float m2=wsum64(gvv)*(1.f/64.f);
  float d2=gvv-m2;
  float v2=wsum64(d2*d2)*(1.f/64.f);
  float gg = fmaxf(d2*rsqrtf(v2+1e-5f)*glng[lane]+glnb[lane],0.f)*tanhf(alpha_p[0]);
  float sm_ = wsum64(fr+gg)*(1.f/128.f);
  float da=fr-sm_, db=gg-sm_;
  float vv = wsum64(da*da+db*db)*(1.f/128.f);
  float rs = rsqrtf(vv+1e-5f);
  int t = f & 255;
  fused[(size_t)f*128+lane]     = da*rs*flng[lane]+flnb[lane]         + pe_val(t,lane);
  fused[(size_t)f*128+64+lane]  = db*rs*flng[64+lane]+flnb[64+lane]   + pe_val(t,64+lane);
}

// ---------------- temporal QKV: Y = X@W + b  (grid (128, 3): oc chunk per blockIdx.y)
__global__ __launch_bounds__(256) void tqkv_gemm_kernel(
    const float* __restrict__ X, float* __restrict__ Y,
    const float* __restrict__ w, const float* __restrict__ b)
{
  __shared__ float Xs[32*128];
  int tid=threadIdx.x;
  const float* Xb = X + (size_t)blockIdx.x*32*128;
  for(int i=tid;i<4096;i+=256) Xs[i]=Xb[i];
  __syncthreads();
  int cg = tid & 31, c0 = cg*4;
  int mg = tid >> 5, m0 = mg*4;
  float* Yb = Y + (size_t)blockIdx.x*32*384;
  int oc = blockIdx.y*128;
  float acc[4][4];
  float4 bv = *(const float4*)&b[oc+c0];
  #pragma unroll
  for(int m=0;m<4;m++){ acc[m][0]=bv.x;acc[m][1]=bv.y;acc[m][2]=bv.z;acc[m][3]=bv.w; }
  for(int k0=0;k0<128;k0+=4){
    float4 w0 = *(const float4*)&w[(k0+0)*384 + oc + c0];
    float4 w1 = *(const float4*)&w[(k0+1)*384 + oc + c0];
    float4 w2 = *(const float4*)&w[(k0+2)*384 + oc + c0];
    float4 w3 = *(const float4*)&w[(k0+3)*384 + oc + c0];
    #pragma unroll
    for(int m=0;m<4;m++){
      float4 xv = *(const float4*)&Xs[(m0+m)*128 + k0];
      acc[m][0] += xv.x*w0.x + xv.y*w1.x + xv.z*w2.x + xv.w*w3.x;
      acc[m][1] += xv.x*w0.y + xv.y*w1.y + xv.z*w2.y + xv.w*w3.y;
      acc[m][2] += xv.x*w0.z + xv.y*w1.z + xv.z*w2.z + xv.w*w3.z;
      acc[m][3] += xv.x*w0.w + xv.y*w1.w + xv.z*w2.w + xv.w*w3.w;
    }
  }
  #pragma unroll
  for(int m=0;m<4;m++){
    float4 yv; yv.x=acc[m][0];yv.y=acc[m][1];yv.z=acc[m][2];yv.w=acc[m][3];
    *(float4*)&Yb[(m0+m)*384 + oc + c0] = yv;
  }
}

// ---------------- split-K temporal attention
__global__ __launch_bounds__(256) void tattn_split_kernel(
    const float* __restrict__ qkv, float* __restrict__ PO,
    float* __restrict__ PM, float* __restrict__ PL)
{
  int b=blockIdx.x, h=blockIdx.y, s=blockIdx.z, tid=threadIdx.x;
  __shared__ float Ksh[32*32];
  __shared__ float Vsh[32*32];
  const float* base = qkv + (size_t)b*256*384;
  int k0 = s*32;
  for(int i=tid;i<1024;i+=256){
    int t=i>>5, d=i&31;
    Ksh[i]=base[(size_t)(k0+t)*384+128+h*32+d];
    Vsh[i]=base[(size_t)(k0+t)*384+256+h*32+d];
  }
  float q[32];
  #pragma unroll
  for(int d=0;d<32;d++) q[d]=base[(size_t)tid*384+h*32+d];
  __syncthreads();
  const float scale=0.17677669529663687f;
  float sc[32];
  float mx=-1e30f;
  #pragma unroll
  for(int k=0;k<32;k++){
    float sv=0.f;
    #pragma unroll
    for(int d=0;d<32;d++) sv += q[d]*Ksh[k*32+d];
    sc[k]=sv*scale;
    mx=fmaxf(mx,sc[k]);
  }
  float l=0.f, o[32];
  #pragma unroll
  for(int d=0;d<32;d++) o[d]=0.f;
  #pragma unroll
  for(int k=0;k<32;k++){
    float p=expf(sc[k]-mx);
    l+=p;
    #pragma unroll
    for(int d=0;d<32;d++) o[d]+=p*Vsh[k*32+d];
  }
  int bh = b*4+h;
  size_t idx = ((size_t)s*64 + bh)*256 + tid;
  PM[idx]=mx; PL[idx]=l;
  float* po = PO + idx*32;
  #pragma unroll
  for(int d=0;d<32;d++) po[d]=o[d];
}

__global__ __launch_bounds__(256) void attn_combine_kernel(
    const float* __restrict__ PO, const float* __restrict__ PM,
    const float* __restrict__ PL, float* __restrict__ obuf)
{
  int tid=threadIdx.x;
  int ql = tid>>5, d = tid&31;
  int bh = blockIdx.x >> 5;
  int qc = blockIdx.x & 31;
  int q = qc*8 + ql;
  float ms[8], ls[8];
  float M=-1e30f;
  #pragma unroll
  for(int s=0;s<8;s++){
    size_t idx = ((size_t)s*64 + bh)*256 + q;
    ms[s]=PM[idx]; ls[s]=PL[idx];
    M=fmaxf(M,ms[s]);
  }
  float L=0.f, ov=0.f;
  #pragma unroll
  for(int s=0;s<8;s++){
    float w = expf(ms[s]-M);
    L += ls[s]*w;
    size_t idx = ((size_t)s*64 + bh)*256 + q;
    ov += w * PO[idx*32 + d];
  }
  int b = bh>>2, h = bh&3;
  obuf[(size_t)(b*256+q)*128 + h*32 + d] = ov / L;
}

// ---------------- fallback monolithic temporal attention
__global__ __launch_bounds__(256) void tattn_kernel(
    const float* __restrict__ qkv, float* __restrict__ obuf)
{
  int b=blockIdx.x, h=blockIdx.y, tid=threadIdx.x;
  __shared__ float Ksh[256*32];
  __shared__ float Vsh[64*32];
  const float* base = qkv + (size_t)b*256*384;
  for(int i=tid;i<8192;i+=256){
    int t=i>>5, d=i&31;
    Ksh[i]=base[t*384+128+h*32+d];
  }
  float q[32];
  #pragma unroll
  for(int d=0;d<32;d++) q[d]=base[(size_t)tid*384+h*32+d];
  __syncthreads();
  const float scale=0.17677669529663687f;
  float mx=-1e30f;
  for(int k=0;k<256;k++){
    float s=0.f;
    #pragma unroll
    for(int d=0;d<32;d++) s += q[d]*Ksh[k*32+d];
    mx=fmaxf(mx,s*scale);
  }
  float l=0.f, o[32];
  #pragma unroll
  for(int d=0;d<32;d++) o[d]=0.f;
  for(int kc=0;kc<256;kc+=64){
    __syncthreads();
    for(int i=tid;i<2048;i+=256){
      int t=i>>5, d=i&31;
      Vsh[i]=base[(size_t)(kc+t)*384+256+h*32+d];
    }
    __syncthreads();
    for(int k2=0;k2<64;k2++){
      float s=0.f;
      #pragma unroll
      for(int d=0;d<32;d++) s += q[d]*Ksh[(kc+k2)*32+d];
      float p=expf(s*scale-mx);
      l+=p;
      #pragma unroll
      for(int d=0;d<32;d++) o[d]+=p*Vsh[k2*32+d];
    }
  }
  float inv=1.f/l;
  float* orow = obuf + (size_t)(b*256+tid)*128 + h*32;
  #pragma unroll
  for(int d=0;d<32;d++) orow[d]=o[d]*inv;
}

// ---------------- temporal out-proj + residual + LN1
__global__ __launch_bounds__(256) void tproj_gemm_kernel(
    const float* __restrict__ O, float* __restrict__ F,
    const float* __restrict__ w, const float* __restrict__ b,
    const float* __restrict__ lg, const float* __restrict__ lb)
{
  __shared__ float Os[32*128];
  __shared__ float Ys[32*128];
  int tid=threadIdx.x;
  const float* Ob = O + (size_t)blockIdx.x*32*128;
  float* Fb = F + (size_t)blockIdx.x*32*128;
  for(int i=tid;i<4096;i+=256) Os[i]=Ob[i];
  __syncthreads();
  int cg = tid & 31, c0 = cg*4;
  int mg = tid >> 5, m0 = mg*4;
  float acc[4][4];
  float4 bv = *(const float4*)&b[c0];
  #pragma unroll
  for(int m=0;m<4;m++){ acc[m][0]=bv.x;acc[m][1]=bv.y;acc[m][2]=bv.z;acc[m][3]=bv.w; }
  for(int k0=0;k0<128;k0+=4){
    float4 w0 = *(const float4*)&w[(k0+0)*128 + c0];
    float4 w1 = *(const float4*)&w[(k0+1)*128 + c0];
    float4 w2 = *(const float4*)&w[(k0+2)*128 + c0];
    float4 w3 = *(const float4*)&w[(k0+3)*128 + c0];
    #pragma unroll
    for(int m=0;m<4;m++){
      float4 xv = *(const float4*)&Os[(m0+m)*128 + k0];
      acc[m][0] += xv.x*w0.x + xv.y*w1.x + xv.z*w2.x + xv.w*w3.x;
      acc[m][1] += xv.x*w0.y + xv.y*w1.y + xv.z*w2.y + xv.w*w3.y;
      acc[m][2] += xv.x*w0.z + xv.y*w1.z + xv.z*w2.z + xv.w*w3.z;
      acc[m][3] += xv.x*w0.w + xv.y*w1.w + xv.z*w2.w + xv.w*w3.w;
    }
  }
  #pragma unroll
  for(int m=0;m<4;m++){
    float4 fv = *(const float4*)&Fb[(m0+m)*128 + c0];
    float4 yv;
    yv.x = fv.x + acc[m][0]; yv.y = fv.y + acc[m][1];
    yv.z = fv.z + acc[m][2]; yv.w = fv.w + acc[m][3];
    *(float4*)&Ys[(m0+m)*128 + c0] = yv;
  }
  __syncthreads();
  int lane = tid & 63, wv = tid >> 6;
  for(int row=wv; row<32; row+=4){
    float e0=Ys[row*128+lane], e1=Ys[row*128+64+lane];
    float mm = wsum64(e0+e1)*(1.f/128.f);
    float d0=e0-mm, d1=e1-mm;
    float rs = rsqrtf(wsum64(d0*d0+d1*d1)*(1.f/128.f)+1e-5f);
    Fb[row*128+lane]    = d0*rs*lg[lane]+lb[lane];
    Fb[row*128+64+lane] = d1*rs*lg[64+lane]+lb[64+lane];
  }
}

// ---------------- Kernel 5: attention pooling over T + classifier
__global__ __launch_bounds__(256) void pool_cls_kernel(
    const float* __restrict__ h2,
    const float* __restrict__ apw,const float* __restrict__ apb,
    const float* __restrict__ c1w,const float* __restrict__ c1b,
    const float* __restrict__ clng,const float* __restrict__ clnb,
    const float* __restrict__ c2w,const float* __restrict__ c2b,
    float* __restrict__ out)
{
  int b=blockIdx.x, tid=threadIdx.x;
  __shared__ float lg[256];
  __shared__ float wt[256];
  __shared__ float invs[1];
  __shared__ float pooled[128];
  __shared__ float z[32];
  const float* H = h2 + (size_t)b*256*128;
  {
    float s=apb[0];
    #pragma unroll
    for(int k=0;k<128;k++) s += H[(size_t)tid*128+k]*apw[k];
    lg[tid]=s;
  }
  __syncthreads();
  if(tid==0){
    float mx=-1e30f;
    for(int i=0;i<256;i++) mx=fmaxf(mx,lg[i]);
    float sm=0.f;
    for(int i=0;i<256;i++){ float e=expf(lg[i]-mx); wt[i]=e; sm+=e; }
    invs[0]=1.f/sm;
  }
  __syncthreads();
  float inv=invs[0];
  if(tid<128){
    float s=0.f;
    for(int t=0;t<256;t++) s += wt[t]*inv*H[(size_t)t*128+tid];
    pooled[tid]=s;
  }
  __syncthreads();
  if(tid<32){
    float s=c1b[tid];
    #pragma unroll
    for(int k=0;k<128;k++) s += pooled[k]*c1w[k*32+tid];
    z[tid]=s;
  }
  __syncthreads();
  if(tid==0){
    float m=0.f;
    for(int i=0;i<32;i++) m+=z[i];
    m *= (1.f/32.f);
    float v=0.f;
    for(int i=0;i<32;i++){ float d=z[i]-m; v+=d*d; }
    v *= (1.f/32.f);
    float rs=rsqrtf(v+1e-5f);
    for(int i=0;i<32;i++) z[i]=fmaxf((z[i]-m)*rs*clng[i]+clnb[i],0.f);
  }
  __syncthreads();
  if(tid<2){
    float s=c2b[tid];
    #pragma unroll
    for(int k=0;k<32;k++) s += z[k]*c2w[k*2+tid];
    out[b*2+tid]=s;
  }
}

extern "C" void kernel_launch(void* const* d_in, const int* in_sizes, int n_in,
                              void* d_out, int out_size, void* d_ws, size_t ws_size,
                              hipStream_t stream) {
  const float* x0 = (const float*)d_in[0];
  const float* x1 = (const float*)d_in[1];
  const float* x2 = (const float*)d_in[2];
  const float* x3 = (const float*)d_in[3];
  const float* x4 = (const float*)d_in[4];
  const float* x5 = (const float*)d_in[5];
  const float* gfeat   = (const float*)d_in[6];
  const float* alpha_p = (const float*)d_in[7];
  const float* g1w = (const float*)d_in[8];
  const float* g1b = (const float*)d_in[9];
  const float* g2w = (const float*)d_in[10];
  const float* g2b = (const float*)d_in[11];
  const float* rlg = (const float*)d_in[12];
  const float* rlb = (const float*)d_in[13];
  const float* spqkvw = (const float*)d_in[14];
  const float* spqkvb = (const float*)d_in[15];
  const float* spow = (const float*)d_in[16];
  const float* spob = (const float*)d_in[17];
  const float* spl1g = (const float*)d_in[18];
  const float* spl1b = (const float*)d_in[19];
  const float* spf1w = (const float*)d_in[20];
  const float* spf1b = (const float*)d_in[21];
  const float* spf2w = (const float*)d_in[22];
  const float* spf2b = (const float*)d_in[23];
  const float* spl2g = (const float*)d_in[24];
  const float* spl2b = (const float*)d_in[25];
  const float* rlogit = (const float*)d_in[26];
  const float* gate1w = (const float*)d_in[27];
  const float* gate1b = (const float*)d_in[28];
  const float* gate2w = (const float*)d_in[29];
  const float* gate2b = (const float*)d_in[30];
  const float* caqkvw = (const float*)d_in[31];
  const float* caqkvb = (const float*)d_in[32];
  const float* caow = (const float*)d_in[33];
  const float* caob = (const float*)d_in[34];
  const float* calng = (const float*)d_in[35];
  const float* calnb = (const float*)d_in[36];
  const float* globw = (const float*)d_in[37];
  const float* globb = (const float*)d_in[38];
  const float* glng = (const float*)d_in[39];
  const float* glnb = (const float*)d_in[40];
  const float* flng = (const float*)d_in[41];
  const float* flnb = (const float*)d_in[42];
  const float* tpqkvw = (const float*)d_in[43];
  const float* tpqkvb = (const float*)d_in[44];
  const float* tpow = (const float*)d_in[45];
  const float* tpob = (const float*)d_in[46];
  const float* tpl1g = (const float*)d_in[47];
  const float* tpl1b = (const float*)d_in[48];
  const float* tpf1w = (const float*)d_in[49];
  const float* tpf1b = (const float*)d_in[50];
  const float* tpf2w = (const float*)d_in[51];
  const float* tpf2b = (const float*)d_in[52];
  const float* tpl2g = (const float*)d_in[53];
  const float* tpl2b = (const float*)d_in[54];
  const float* apw = (const float*)d_in[55];
  const float* apb = (const float*)d_in[56];
  const float* c1w = (const float*)d_in[57];
  const float* c1b = (const float*)d_in[58];
  const float* clng = (const float*)d_in[59];
  const float* clnb = (const float*)d_in[60];
  const float* c2w = (const float*)d_in[61];
  const float* c2b = (const float*)d_in[62];

  float* ws = (float*)d_ws;
  float* tok   = ws;                               // 4096*384
  float* fused = tok   + (size_t)NFRM*384;         // 4096*128
  float* qkv   = fused + (size_t)NFRM*128;         // 4096*384
  float* obuf  = qkv   + (size_t)NFRM*384;         // 4096*128
  float* part  = obuf  + (size_t)NFRM*128;         // partials: 3,145,728 floats
  size_t part_elems = (size_t)2*24576*64;
  unsigned short* pk = (unsigned short*)(part + part_elems);
  unsigned short* sp1h = pk;
  unsigned short* sp1l = sp1h + 131072;
  unsigned short* sp2h = sp1l + 131072;
  unsigned short* sp2l = sp2h + 131072;
  unsigned short* tp1h = sp2l + 131072;
  unsigned short* tp1l = tp1h + 262144;
  unsigned short* tp2h = tp1l + 262144;
  unsigned short* tp2l = tp2h + 262144;
  size_t pack_ushorts = 4*131072 + 4*262144;
  size_t need = ((size_t)NFRM*384 + NFRM*128 + NFRM*384 + NFRM*128 + part_elems)*4
              + pack_ushorts*2;
  bool mfma_ok = (ws_size >= need);

  float* attnPO = (float*)(pk + pack_ushorts);
  float* attnPM = attnPO + (size_t)8*64*256*32;
  float* attnPL = attnPM + (size_t)8*64*256;
  size_t need2 = need + ((size_t)8*64*256*32 + 2*(size_t)8*64*256)*4;
  bool attn_ok = (ws_size >= need2);

  if(mfma_ok){
    pack_all_kernel<<<1536,64,0,stream>>>(spf1w,spf2w,tpf1w,tpf2w,
                                          sp1h,sp1l,sp2h,sp2l,tp1h,tp1l,tp2h,tp2l);
  }

  gcn_kernel<<<dim3(NFRM/2,6),128,0,stream>>>(x0,x1,x2,x3,x4,x5,g1w,g1b,g2w,g2b,rlg,rlb,tok);
  sp_attn_kernel<<<NFRM/4,256,0,stream>>>(tok,spqkvw,spqkvb,spow,spob,spl1g,spl1b);
  if(mfma_ok){
    ffn_mfma_partial<64,2><<<dim3(768,2),256,0,stream>>>(tok,part,sp1h,sp1l,spf1b,sp2h,sp2l);
    // combine folded into fuse_kernel
    fuse_kernel<<<NFRM/4,256,0,stream>>>(tok,part,1,spf2b,spl2g,spl2b,
                                      gfeat,alpha_p,rlogit,gate1w,gate1b,gate2w,gate2b,
                                      caqkvw,caqkvb,caow,caob,calng,calnb,
                                      globw,globb,glng,glnb,flng,flnb,fused);
  } else {
    ffn_ln_kernel<64,32><<<768,256,0,stream>>>(tok,tok,spf1w,spf1b,spf2w,spf2b,spl2g,spl2b);
    fuse_kernel<<<NFRM/4,256,0,stream>>>(tok,part,0,spf2b,spl2g,spl2b,
                                      gfeat,alpha_p,rlogit,gate1w,gate1b,gate2w,gate2b,
                                      caqkvw,caqkvb,caow,caob,calng,calnb,
                                      globw,globb,glng,glnb,flng,flnb,fused);
  }
  tqkv_gemm_kernel<<<dim3(128,3),256,0,stream>>>(fused,qkv,tpqkvw,tpqkvb);
  if(attn_ok){
    tattn_split_kernel<<<dim3(NBATCH,4,8),256,0,stream>>>(qkv,attnPO,attnPM,attnPL);
    attn_combine_kernel<<<64*32,256,0,stream>>>(attnPO,attnPM,attnPL,obuf);
  } else {
    tattn_kernel<<<dim3(NBATCH,4),256,0,stream>>>(qkv,obuf);
  }
  tproj_gemm_kernel<<<128,256,0,stream>>>(obuf,fused,tpow,tpob,tpl1g,tpl1b);
  if(mfma_ok){
    ffn_mfma_partial<128,4><<<dim3(128,4),256,0,stream>>>(fused,part,tp1h,tp1l,tpf1b,tp2h,tp2l);
    ffn_combine_kernel<128,4><<<NFRM/4,256,0,stream>>>(fused,part,obuf,tpf2b,tpl2g,tpl2b);
  } else {
    ffn_ln_kernel<128,16><<<256,256,0,stream>>>(fused,obuf,tpf1w,tpf1b,tpf2w,tpf2b,tpl2g,tpl2b);
  }
  pool_cls_kernel<<<NBATCH,256,0,stream>>>(obuf,apw,apb,c1w,c1b,clng,clnb,c2w,c2b,(float*)d_out);
}